// Round 6
// baseline (62312.799 us; speedup 1.0000x reference)
//
#include <hip/hip_runtime.h>
#include <cstdint>
#include <cstddef>

// ---------------- problem constants ----------------
namespace {
constexpr int Bb = 8, Ss = 2048, Ee = 256, Hh = 256, G4 = 1024, Tt = 12;
constexpr int NTOK = Bb * Ss;              // 16384 rows
constexpr int NC = 256, LCH = 64;          // viterbi chunking: 256 chunks x 64 steps
constexpr float FNEG = -10000.0f;
constexpr int START_TAG = 10, STOP_TAG = 11;

// ---------------- workspace layout (bytes) ----------------
constexpr size_t OFF_XS    = 0;                         // [16384][256] f32 gathered embeddings
constexpr size_t SZ_XS     = (size_t)NTOK * Ee * 4;
constexpr size_t OFF_WT    = OFF_XS + SZ_XS;            // [2][256][1024] f32 w_ih transposed
constexpr size_t SZ_WT     = (size_t)2 * Ee * G4 * 4;
constexpr size_t OFF_XPF   = OFF_WT + SZ_WT;            // [2048][8][1024] f32 x-proj fwd (bias folded)
constexpr size_t SZ_XP     = (size_t)Ss * Bb * G4 * 4;
constexpr size_t OFF_XPB   = OFF_XPF + SZ_XP;
constexpr size_t OFF_HF    = OFF_XPB + SZ_XP;           // [2048][8][256] f32 fwd hidden history
constexpr size_t SZ_H      = (size_t)Ss * Bb * Hh * 4;
constexpr size_t OFF_HB    = OFF_HF + SZ_H;
constexpr size_t OFF_FEATS = OFF_HB + SZ_H;             // [16384][12] f32
constexpr size_t SZ_FEATS  = (size_t)NTOK * Tt * 4;
constexpr size_t OFF_PMAT  = OFF_FEATS + SZ_FEATS;      // [256][144] f32 chunk max-plus mats
constexpr size_t SZ_PMAT   = (size_t)NC * 144 * 4;
constexpr size_t OFF_FVIN  = OFF_PMAT + SZ_PMAT;        // [256][12] f32 chunk-entry fv
constexpr size_t SZ_FVIN   = (size_t)NC * Tt * 4;
constexpr size_t OFF_BPTR  = OFF_FVIN + SZ_FVIN;        // [16384] u64 packed 12x4bit backptrs
constexpr size_t SZ_BPTR   = (size_t)NTOK * 8;
constexpr size_t OFF_CMAP  = OFF_BPTR + SZ_BPTR;        // [256][12] int chunk composed maps
constexpr size_t SZ_CMAP   = (size_t)NC * Tt * 4;
constexpr size_t OFF_EVEC  = OFF_CMAP + SZ_CMAP;        // [256] int tag at chunk-end
constexpr size_t SZ_EVEC   = (size_t)NC * 4;
constexpr size_t OFF_BEST  = OFF_EVEC + SZ_EVEC;        // [1] int
constexpr size_t SZ_BEST   = 256;
constexpr size_t OFF_HD    = OFF_BEST + SZ_BEST;        // (legacy MALL exchange buf, unused)
constexpr size_t SZ_HD     = (size_t)2 * 2 * 2048 * 8;
constexpr size_t OFF_EPOCH = OFF_HD + SZ_HD;            // [1] u32 per-run epoch (realtime fold)
constexpr size_t SZ_EPOCH  = 256;
constexpr size_t WS_NEED   = OFF_EPOCH + SZ_EPOCH;      // ~179 MB (unchanged vs prior rounds)

// Per-XCD exchange buffers live INSIDE the feats region (feats is written
// only AFTER k_lstm completes, so the space is dead during the recurrence):
//   xhd: [8 xcd][2 dir][2 par][2048] u64 tagged h   = 512 KB
//   xtk: [8 xcd] u32 arrival tickets, 128B apart    = 1 KB
constexpr size_t OFF_XHD   = OFF_FEATS;
constexpr size_t SZ_XHD    = (size_t)8 * 2 * 2 * 2048 * 8;   // 524288
constexpr size_t OFF_XTK   = OFF_XHD + SZ_XHD;
constexpr size_t SZ_XTK    = 1024;
static_assert(SZ_XHD + SZ_XTK <= SZ_FEATS, "exchange buffers must fit in feats region");

// Anti-hang valve only; with epoch tags it should never fire. If it does,
// the group dies cleanly (~0.2s worst) without writing.
constexpr int POLL_TMO = 1 << 19;

__device__ __forceinline__ float4 f4fma(float a, float4 b, float4 c) {
  c.x = fmaf(a, b.x, c.x); c.y = fmaf(a, b.y, c.y);
  c.z = fmaf(a, b.z, c.z); c.w = fmaf(a, b.w, c.w);
  return c;
}

// sum across the 4 lanes of a quad via DPP quad_perm -- VALU pipe only.
__device__ __forceinline__ float quad_sum(float x) {
  float y = __int_as_float(
      __builtin_amdgcn_update_dpp(0, __float_as_int(x), 0xB1, 0xF, 0xF, true));
  x += y;  // + lane^1
  y = __int_as_float(
      __builtin_amdgcn_update_dpp(0, __float_as_int(x), 0x4E, 0xF, 0xF, true));
  return x + y;  // + lane^2
}
__device__ __forceinline__ float4 quad_sum4(float4 v) {
  v.x = quad_sum(v.x); v.y = quad_sum(v.y);
  v.z = quad_sum(v.z); v.w = quad_sum(v.w);
  return v;
}

// L2-point exchange primitives (R9, proven: 13.3ms -> 2.05ms).
// CDNA vector L1 is write-through: a plain global store lands in the XCD's
// shared L2. Loads with the sc0 cache bit BYPASS the (potentially stale)
// per-CU L1 and are served from that same L2 -- normal read path, no atomic
// unit, no MALL visit (R8 PMC: scope-qualified atomics still executed
// memory-side, 26 GB HBM traffic; these don't).
__device__ __forceinline__ unsigned long long l2_load_u64(
    const unsigned long long* p) {
  unsigned long long v;
  asm volatile("global_load_dwordx2 %0, %1, off sc0\n\t"
               "s_waitcnt vmcnt(0)"
               : "=v"(v) : "v"(p) : "memory");
  return v;
}
__device__ __forceinline__ void l2_store_u64(unsigned long long* p,
                                             unsigned long long v) {
  asm volatile("global_store_dwordx2 %0, %1, off sc0"
               :: "v"(p), "v"(v) : "memory");
}
}  // namespace

// ---------------- init: zero exchange buffers, tickets; stamp run epoch ----------------
// R10: tags are now epoch-salted -- (epoch20<<12)|step -- where epoch20 is a
// fold of s_memrealtime() taken HERE, fresh on every launch/graph-replay.
// R9 post-mortem: un-salted tags (identical 1..2048 every run) let stale
// L2/MALL lines from a previous run or ws-poison satisfy polls early, which
// broke the skew-bound invariant -> writer overwrote unconsumed slots ->
// reader livelock -> timeout death -> partial hist -> absmax=128 + a 22.6ms
// outlier dispatch. Epoch salting makes every stale line fail the compare
// (collision ~2^-20, and completed-run collisions carry identical data).
__global__ __launch_bounds__(256) void k_init(unsigned long long* xhd, unsigned* xtk,
                                              unsigned* epoch) {
  int g = blockIdx.x * 256 + threadIdx.x;
  for (int i = g; i < 8 * 8192; i += 32 * 256) xhd[i] = 0ULL;
  if (g < 256) xtk[g] = 0u;
  if (g == 0) {
    unsigned long long rt = __builtin_amdgcn_s_memrealtime();
    unsigned ep = (unsigned)((rt ^ (rt >> 20) ^ (rt >> 40)) & 0xFFFFFu);
    *epoch = ep;
  }
}

// ---------------- gather embeddings: xs[r=t*8+b][k] = emb[sentence[b][t]][k] ----------------
__global__ __launch_bounds__(256) void k_gather(const int* __restrict__ sent,
                                                const float* __restrict__ emb,
                                                float* __restrict__ xs) {
  int rr = threadIdx.x >> 3, p = threadIdx.x & 7;
  int r = blockIdx.x * 32 + rr;
  int tg = r >> 3, bg = r & 7;
  int tok = sent[bg * Ss + tg];
  const float4* src = (const float4*)(emb + (size_t)tok * Ee) + p * 8;
  float4* dst = (float4*)(xs + (size_t)r * Ee) + p * 8;
#pragma unroll
  for (int i = 0; i < 8; ++i) dst[i] = src[i];
}

// ---------------- transpose w_ih -> wT[d][k][n] ----------------
__global__ __launch_bounds__(256) void k_transpose(const float* __restrict__ w_f,
                                                   const float* __restrict__ w_b,
                                                   float* __restrict__ wT) {
  int idx = blockIdx.x * 256 + threadIdx.x;
  if (idx >= 2 * Ee * G4) return;
  int d = idx >> 18;
  int rem = idx & 262143;
  int k = rem >> 10, n = rem & 1023;
  const float* w = d ? w_b : w_f;
  wT[idx] = w[n * Ee + k];
}

// ---------------- input projection GEMM: xp[r][n] = xs[r][:] . w_ih[n][:] + bias[n] ----------------
__global__ __launch_bounds__(256) void k_inproj(const float* __restrict__ xs,
                                                const float* __restrict__ wT,
                                                const float* __restrict__ b_f,
                                                const float* __restrict__ b_b,
                                                float* __restrict__ xpf,
                                                float* __restrict__ xpb) {
  const int dir = blockIdx.z;
  const float* wTd = wT + (size_t)dir * (Ee * G4);
  const float* bv = dir ? b_b : b_f;
  float* xp = dir ? xpb : xpf;
  const int rg = threadIdx.x >> 5, cg = threadIdx.x & 31;
  const int rbase = blockIdx.x * 32 + rg * 4;
  const int c0 = blockIdx.y * 128 + cg * 4;
  const float4* ap0 = (const float4*)(xs + (size_t)(rbase + 0) * Ee);
  const float4* ap1 = (const float4*)(xs + (size_t)(rbase + 1) * Ee);
  const float4* ap2 = (const float4*)(xs + (size_t)(rbase + 2) * Ee);
  const float4* ap3 = (const float4*)(xs + (size_t)(rbase + 3) * Ee);
  float4 acc0 = {0,0,0,0}, acc1 = {0,0,0,0}, acc2 = {0,0,0,0}, acc3 = {0,0,0,0};
#pragma unroll 4
  for (int k4 = 0; k4 < 64; ++k4) {
    float4 a0 = ap0[k4], a1 = ap1[k4], a2 = ap2[k4], a3 = ap3[k4];
    const float* wb = wTd + (size_t)(k4 * 4) * G4 + c0;
    float4 b0 = *(const float4*)(wb);
    float4 b1 = *(const float4*)(wb + G4);
    float4 b2 = *(const float4*)(wb + 2 * G4);
    float4 b3 = *(const float4*)(wb + 3 * G4);
    acc0 = f4fma(a0.x, b0, acc0); acc0 = f4fma(a0.y, b1, acc0);
    acc0 = f4fma(a0.z, b2, acc0); acc0 = f4fma(a0.w, b3, acc0);
    acc1 = f4fma(a1.x, b0, acc1); acc1 = f4fma(a1.y, b1, acc1);
    acc1 = f4fma(a1.z, b2, acc1); acc1 = f4fma(a1.w, b3, acc1);
    acc2 = f4fma(a2.x, b0, acc2); acc2 = f4fma(a2.y, b1, acc2);
    acc2 = f4fma(a2.z, b2, acc2); acc2 = f4fma(a2.w, b3, acc2);
    acc3 = f4fma(a3.x, b0, acc3); acc3 = f4fma(a3.y, b1, acc3);
    acc3 = f4fma(a3.z, b2, acc3); acc3 = f4fma(a3.w, b3, acc3);
  }
  float4 bias = *(const float4*)(bv + c0);
  acc0.x += bias.x; acc0.y += bias.y; acc0.z += bias.z; acc0.w += bias.w;
  acc1.x += bias.x; acc1.y += bias.y; acc1.z += bias.z; acc1.w += bias.w;
  acc2.x += bias.x; acc2.y += bias.y; acc2.z += bias.z; acc2.w += bias.w;
  acc3.x += bias.x; acc3.y += bias.y; acc3.z += bias.z; acc3.w += bias.w;
  *(float4*)(xp + (size_t)(rbase + 0) * G4 + c0) = acc0;
  *(float4*)(xp + (size_t)(rbase + 1) * G4 + c0) = acc1;
  *(float4*)(xp + (size_t)(rbase + 2) * G4 + c0) = acc2;
  *(float4*)(xp + (size_t)(rbase + 3) * G4 + c0) = acc3;
}

// ---------------- persistent bidirectional LSTM recurrence ----------------
// R10 = R9 (same-XCD groups + sc0 L2-point exchange; 2.05ms steady, proven)
//       + epoch-salted tags (correctness hardening, see k_init comment).
//   - 256 blocks; each reads XCC_ID, takes a per-XCD ticket (agent atomic,
//     once). First 16 blocks of each XCD form a complete worker group
//     (wg 0..7 fwd, 8..15 bwd) on that XCD's PRIVATE buffer; later arrivals
//     exit. Pigeonhole guarantees >=1 complete group; all complete groups
//     compute redundantly and write identical hist (benign).
//   - exchange = tag-in-data u64 [tag:32|f32:32], tag=(epoch20<<12)|step,
//     parity double-buffer; plain write-through store publishes into the
//     XCD L2, sc0 load polls it. No atomics, no MALL, ~1us/step.
// Starvation-freedom: with epoch salting, a slot polled for tag T holds only
// {non-matching stale, T-2's tag, T} -- overwrite (T -> T+2) requires the
// writer's whole WG to have consumed tag T+1, which requires all readers to
// have passed tag T. Stale lines never match, so the bound cannot be skipped.
__global__ __launch_bounds__(512, 2) void k_lstm(
    const float* __restrict__ whh_f, const float* __restrict__ whh_b,
    const float* __restrict__ h0, const float* __restrict__ c0,
    const float* __restrict__ xpf, const float* __restrict__ xpb,
    float* __restrict__ hist_f, float* __restrict__ hist_b,
    unsigned long long* xhd, unsigned* xtk, const unsigned* epoch) {
  __shared__ __align__(16) float h_lds[2048];   // [k][b]
  __shared__ float part[128 * 33];              // [row][ks_hi*8 + b], pad 33
  __shared__ int s_role, s_xcc, wg_dead;
  __shared__ unsigned s_ep;

  const int t = threadIdx.x;
  if (t == 0) {
    unsigned xcc = __builtin_amdgcn_s_getreg((3 << 11) | 20) & 7u;  // hwreg(XCC_ID=20,0,4)
    unsigned r = __hip_atomic_fetch_add(xtk + xcc * 32, 1u,
                                        __ATOMIC_RELAXED, __HIP_MEMORY_SCOPE_AGENT);
    s_role = (int)r;
    s_xcc = (int)xcc;
    wg_dead = 0;
    // epoch via agent-scope atomic load: executes at the MALL, so it sees
    // k_init's kernel-end writeback regardless of local L2 staleness.
    s_ep = __hip_atomic_load(epoch, __ATOMIC_RELAXED, __HIP_MEMORY_SCOPE_AGENT);
  }
  __syncthreads();
  if (s_role >= 16) return;   // uniform block exit
  const int wg = s_role, dir = wg >> 3, j0 = (wg & 7) * 32;
  const unsigned epbase = s_ep << 12;   // tag = epbase | step
  const float* whh = dir ? whh_b : whh_f;
  const float* xp = dir ? xpb : xpf;
  float* hist = dir ? hist_b : hist_f;
  unsigned long long* hd = xhd + (size_t)s_xcc * 8192 + (size_t)dir * 4096;

  // FMA-thread mapping: lane = rg(16) x ks_lo(4); wave = ks_hi(4) x bs(2)
  const int wave = t >> 6, lane = t & 63;
  const int ks_hi = wave & 3, bs = wave >> 2;   // wave-uniform
  const int rg = lane >> 2, ks_lo = lane & 3;   // per-lane
  // weights: 8 rows x 16 k per thread, k = ks_hi*64 + i*4 + ks_lo
  float wreg[8][16];
#pragma unroll
  for (int r = 0; r < 8; ++r) {
    const int row = rg * 8 + r;
    const int n = ((row >> 5) << 8) + j0 + (row & 31);
    const float* wb = whh + (size_t)n * Hh + ks_hi * 64 + ks_lo;
#pragma unroll
    for (int i = 0; i < 16; ++i) wreg[r][i] = wb[i * 4];
  }
  // gate-thread mapping (t<256): owns hidden unit (j0+jj, batch bg)
  const int jj = t >> 3, bg = t & 7;
  float c_reg = 0.0f;
  if (t < 256) c_reg = c0[dir * 2048 + bg * Hh + j0 + jj];

  for (int s = 0; s < Ss; ++s) {
    const int tg = dir ? (Ss - 1 - s) : s;
    // gate threads prefetch their 4 x-proj values (overlap the wait)
    float xq0 = 0.f, xq1 = 0.f, xq2 = 0.f, xq3 = 0.f;
    if (t < 256) {
      const float* xpt = xp + (size_t)tg * 8192 + bg * G4 + j0 + jj;
      xq0 = xpt[0]; xq1 = xpt[256]; xq2 = xpt[512]; xq3 = xpt[768];
    }
    // fill h_lds[k][b] with h_{s-1}
    if (s == 0) {
#pragma unroll
      for (int i = 0; i < 4; ++i) {
        int idx = t * 4 + i;
        h_lds[idx] = h0[dir * 2048 + (idx & 7) * Hh + (idx >> 3)];
      }
    } else {
      // poll own 4 tagged words at the XCD L2 until tag == epbase|s
      unsigned long long* buf = hd + (size_t)((s - 1) & 1) * 2048 + 4 * t;
      const unsigned want = epbase | (unsigned)s;
      int to = 0;
      unsigned long long w0, w1, w2, w3;
      w0 = l2_load_u64(buf + 0);
      while ((unsigned)(w0 >> 32) != want && ++to < POLL_TMO) {
        __builtin_amdgcn_s_sleep(1);
        w0 = l2_load_u64(buf + 0);
      }
      w1 = l2_load_u64(buf + 1);
      while ((unsigned)(w1 >> 32) != want && ++to < POLL_TMO) {
        __builtin_amdgcn_s_sleep(1);
        w1 = l2_load_u64(buf + 1);
      }
      w2 = l2_load_u64(buf + 2);
      while ((unsigned)(w2 >> 32) != want && ++to < POLL_TMO) {
        __builtin_amdgcn_s_sleep(1);
        w2 = l2_load_u64(buf + 2);
      }
      w3 = l2_load_u64(buf + 3);
      while ((unsigned)(w3 >> 32) != want && ++to < POLL_TMO) {
        __builtin_amdgcn_s_sleep(1);
        w3 = l2_load_u64(buf + 3);
      }
      if (to >= POLL_TMO) wg_dead = 1;
      float4 hv4;
      hv4.x = __uint_as_float((unsigned)w0);
      hv4.y = __uint_as_float((unsigned)w1);
      hv4.z = __uint_as_float((unsigned)w2);
      hv4.w = __uint_as_float((unsigned)w3);
      ((float4*)h_lds)[t] = hv4;
    }
    __syncthreads();  // B1: h_lds ready, prev-step part[] reusable
    if (wg_dead) return;  // dead group: exit before writing anything this step
    // recurrent GEMM: 8 rows x 16 k x 4 b per thread
    float4 acc0 = {0,0,0,0}, acc1 = {0,0,0,0}, acc2 = {0,0,0,0}, acc3 = {0,0,0,0};
    float4 acc4 = {0,0,0,0}, acc5 = {0,0,0,0}, acc6 = {0,0,0,0}, acc7 = {0,0,0,0};
    const float* hbase = h_lds + ks_hi * 512 + ks_lo * 8 + bs * 4;
#pragma unroll
    for (int i = 0; i < 16; ++i) {
      float4 h4 = *(const float4*)(hbase + i * 32);
      acc0 = f4fma(wreg[0][i], h4, acc0);
      acc1 = f4fma(wreg[1][i], h4, acc1);
      acc2 = f4fma(wreg[2][i], h4, acc2);
      acc3 = f4fma(wreg[3][i], h4, acc3);
      acc4 = f4fma(wreg[4][i], h4, acc4);
      acc5 = f4fma(wreg[5][i], h4, acc5);
      acc6 = f4fma(wreg[6][i], h4, acc6);
      acc7 = f4fma(wreg[7][i], h4, acc7);
    }
    // full quad sums in every lane (VALU pipe)
    acc0 = quad_sum4(acc0); acc1 = quad_sum4(acc1);
    acc2 = quad_sum4(acc2); acc3 = quad_sum4(acc3);
    acc4 = quad_sum4(acc4); acc5 = quad_sum4(acc5);
    acc6 = quad_sum4(acc6); acc7 = quad_sum4(acc7);
    // lane ks_lo=q emits rows 2q,2q+1 -- CONSTANT-index cndmask select
    // (R4 post-mortem: acc[2*ks_lo] dynamic indexing sent acc[] to scratch)
    float4 s0 = acc0, s1 = acc1;
    if (ks_lo == 1) { s0 = acc2; s1 = acc3; }
    if (ks_lo == 2) { s0 = acc4; s1 = acc5; }
    if (ks_lo == 3) { s0 = acc6; s1 = acc7; }
    {
      const int row0 = rg * 8 + 2 * ks_lo;
      *(float4*)&part[row0 * 33 + ks_hi * 8 + bs * 4] = s0;
      *(float4*)&part[(row0 + 1) * 33 + ks_hi * 8 + bs * 4] = s1;
    }
    __syncthreads();  // B2: part[] complete
    // fused ks_hi-reduce + gates (PyTorch order i,f,g,o) + publish + hist
    if (t < 256) {
      float z0 = xq0, z1 = xq1, z2 = xq2, z3 = xq3;
#pragma unroll
      for (int kq = 0; kq < 4; ++kq) {
        z0 += part[(jj) * 33 + kq * 8 + bg];
        z1 += part[(32 + jj) * 33 + kq * 8 + bg];
        z2 += part[(64 + jj) * 33 + kq * 8 + bg];
        z3 += part[(96 + jj) * 33 + kq * 8 + bg];
      }
      float iv = 1.0f / (1.0f + expf(-z0));
      float fv = 1.0f / (1.0f + expf(-z1));
      float gv = tanhf(z2);
      float ov = 1.0f / (1.0f + expf(-z3));
      c_reg = fv * c_reg + iv * gv;
      float hv = ov * tanhf(c_reg);
      // publish tagged word: [epbase|(s+1) : h bits], slot = channel*8 + batch
      unsigned long long wv =
          ((unsigned long long)(epbase | (unsigned)(s + 1)) << 32) |
          (unsigned long long)__float_as_uint(hv);
      unsigned long long* bufw = hd + (size_t)(s & 1) * 2048;
      l2_store_u64(bufw + (size_t)(j0 + jj) * 8 + bg, wv);
      hist[(size_t)tg * 2048 + bg * Hh + j0 + jj] = hv;
    }
    // no publish-side drain: readers detect tags at the XCD L2 directly
  }
}

// ---------------- feats = [hf|hb] @ W_out^T + b_out ----------------
__global__ __launch_bounds__(256) void k_feats(const float* __restrict__ hist_f,
                                               const float* __restrict__ hist_b,
                                               const float* __restrict__ Wout,
                                               const float* __restrict__ bout,
                                               float* __restrict__ feats) {
  __shared__ float wsh[Tt * 512];
  __shared__ float bsh[Tt];
  for (int i = threadIdx.x; i < Tt * 512; i += 256) wsh[i] = Wout[i];
  if (threadIdx.x < Tt) bsh[threadIdx.x] = bout[threadIdx.x];
  __syncthreads();
  int r = blockIdx.x * 256 + threadIdx.x;
  int bq = r >> 11, sq = r & 2047;
  const float4* hf4 = (const float4*)(hist_f + (size_t)sq * 2048 + bq * Hh);
  const float4* hb4 = (const float4*)(hist_b + (size_t)sq * 2048 + bq * Hh);
  float acc[Tt];
#pragma unroll
  for (int j = 0; j < Tt; ++j) acc[j] = bsh[j];
  for (int k4 = 0; k4 < 64; ++k4) {
    float4 x = hf4[k4];
#pragma unroll
    for (int j = 0; j < Tt; ++j) {
      float4 w = *(const float4*)&wsh[j * 512 + k4 * 4];
      acc[j] = fmaf(x.x, w.x, fmaf(x.y, w.y, fmaf(x.z, w.z, fmaf(x.w, w.w, acc[j]))));
    }
  }
  for (int k4 = 0; k4 < 64; ++k4) {
    float4 x = hb4[k4];
#pragma unroll
    for (int j = 0; j < Tt; ++j) {
      float4 w = *(const float4*)&wsh[j * 512 + 256 + k4 * 4];
      acc[j] = fmaf(x.x, w.x, fmaf(x.y, w.y, fmaf(x.z, w.z, fmaf(x.w, w.w, acc[j]))));
    }
  }
#pragma unroll
  for (int j = 0; j < Tt; ++j) feats[(size_t)r * Tt + j] = acc[j];
}

// ---------------- Viterbi phase 1: per-chunk max-plus matrix product ----------------
__global__ __launch_bounds__(192) void k_vit_chunkmat(const float* __restrict__ feats,
                                                      const float* __restrict__ trans,
                                                      float* __restrict__ pmat) {
  __shared__ float R[2][144];
  __shared__ float fe[LCH * Tt];
  __shared__ float ts[144];
  const int t = threadIdx.x, c = blockIdx.x;
  for (int i = t; i < LCH * Tt; i += 192) fe[i] = feats[(size_t)c * LCH * Tt + i];
  if (t < 144) ts[t] = trans[t];
  __syncthreads();
  int j = 0, k = 0;
  float trow[12];
  if (t < 144) {
    j = t / 12; k = t - j * 12;
#pragma unroll
    for (int m = 0; m < 12; ++m) trow[m] = ts[j * 12 + m];
    R[0][t] = ts[t] + fe[j];  // A_{t0}
  }
  __syncthreads();
  for (int i = 1; i < LCH; ++i) {
    int p = (i - 1) & 1;
    if (t < 144) {
      float m = trow[0] + R[p][k];
#pragma unroll
      for (int mm = 1; mm < 12; ++mm) m = fmaxf(m, trow[mm] + R[p][mm * 12 + k]);
      R[p ^ 1][t] = m + fe[i * 12 + j];
    }
    __syncthreads();
  }
  if (t < 144) pmat[(size_t)c * 144 + t] = R[(LCH - 1) & 1][t];
}

// ---------------- Viterbi phase 2: sequential scan over chunk matrices ----------------
__global__ __launch_bounds__(192) void k_vit_scan(const float* __restrict__ pmat,
                                                  const float* __restrict__ trans,
                                                  float* __restrict__ fvin,
                                                  float* __restrict__ dout,
                                                  int* __restrict__ best) {
  __shared__ float fv[12];
  __shared__ float sl[144];
  __shared__ float term[12];
  const int t = threadIdx.x;
  const int j = t / 12, k = t - j * 12;
  if (t < 12) fv[t] = (t == START_TAG) ? 0.0f : FNEG;
  float pv = (t < 144) ? pmat[t] : 0.0f;
  __syncthreads();
  for (int c = 0; c < NC; ++c) {
    if (t < 12) fvin[c * 12 + t] = fv[t];
    float pnext = (t < 144 && c + 1 < NC) ? pmat[(size_t)(c + 1) * 144 + t] : 0.0f;
    if (t < 144) sl[t] = pv + fv[k];
    __syncthreads();
    if (t < 12) {
      float m = sl[t * 12];
#pragma unroll
      for (int kk = 1; kk < 12; ++kk) m = fmaxf(m, sl[t * 12 + kk]);
      fv[t] = m;
    }
    __syncthreads();
    pv = pnext;
  }
  if (t < 12) term[t] = fv[t] + trans[STOP_TAG * 12 + t];
  __syncthreads();
  if (t == 0) {
    float m = term[0]; int a = 0;
    for (int q = 1; q < 12; ++q) { if (term[q] > m) { m = term[q]; a = q; } }
    dout[0] = m;
    best[0] = a;
  }
}

// ---------------- Viterbi phase 3: replay chunks -> packed backpointers ----------------
__global__ __launch_bounds__(64) void k_vit_replay(const float* __restrict__ feats,
                                                   const float* __restrict__ trans,
                                                   const float* __restrict__ fvin,
                                                   unsigned long long* __restrict__ bptr) {
  __shared__ float fe[LCH * Tt];
  __shared__ float fv[12];
  __shared__ int bpn[12];
  const int t = threadIdx.x, c = blockIdx.x;
  for (int i = t; i < LCH * Tt; i += 64) fe[i] = feats[(size_t)c * LCH * Tt + i];
  float trow[12];
  if (t < 12) {
#pragma unroll
    for (int m = 0; m < 12; ++m) trow[m] = trans[t * 12 + m];
    fv[t] = fvin[c * 12 + t];
  }
  __syncthreads();
  for (int i = 0; i < LCH; ++i) {
    float nm = 0.0f;
    if (t < 12) {
      float m = fv[0] + trow[0]; int a = 0;
#pragma unroll
      for (int k = 1; k < 12; ++k) {
        float v = fv[k] + trow[k];
        if (v > m) { m = v; a = k; }   // first-max wins, matches jnp.argmax
      }
      nm = m + fe[i * 12 + t];
      bpn[t] = a;
    }
    __syncthreads();
    if (t < 12) fv[t] = nm;
    if (t == 0) {
      unsigned long long bp = 0;
#pragma unroll
      for (int jq = 0; jq < 12; ++jq)
        bp |= (unsigned long long)(unsigned)bpn[jq] << (4 * jq);
      bptr[(size_t)c * LCH + i] = bp;
    }
    __syncthreads();
  }
}

// ---------------- backtrace phase A: compose per-chunk tag maps ----------------
__global__ __launch_bounds__(64) void k_bt_chunk(const unsigned long long* __restrict__ bptr,
                                                 int* __restrict__ cmap) {
  __shared__ unsigned long long bp[LCH];
  const int t = threadIdx.x, c = blockIdx.x;
  if (t < LCH) bp[t] = bptr[(size_t)c * LCH + t];
  __syncthreads();
  if (t < 12) {
    int v = t;
    for (int i = LCH - 1; i >= 0; --i) v = (int)((bp[i] >> (4 * v)) & 15ULL);
    cmap[c * 12 + t] = v;
  }
}

// ---------------- backtrace phase B: scan chunk maps ----------------
__global__ __launch_bounds__(256) void k_bt_scan(const int* __restrict__ cmap,
                                                 const int* __restrict__ best,
                                                 int* __restrict__ evec) {
  __shared__ int cm[NC * 12];
  __shared__ int es[NC];
  const int t = threadIdx.x;
  for (int i = t; i < NC * 12; i += 256) cm[i] = cmap[i];
  __syncthreads();
  if (t == 0) {
    int tag = best[0];
    es[NC - 1] = tag;
    for (int c = NC - 1; c >= 1; --c) { tag = cm[c * 12 + tag]; es[c - 1] = tag; }
  }
  __syncthreads();
  evec[t] = es[t];
}

// ---------------- backtrace phase C: emit path ----------------
__global__ __launch_bounds__(64) void k_bt_replay(const unsigned long long* __restrict__ bptr,
                                                  const int* __restrict__ evec,
                                                  float* __restrict__ dout) {
  __shared__ unsigned long long bp[LCH];
  __shared__ int tgs[LCH];
  const int t = threadIdx.x, c = blockIdx.x;
  if (t < LCH) bp[t] = bptr[(size_t)c * LCH + t];
  __syncthreads();
  if (t == 0) {
    int tag = evec[c];  // tag at global index (c+1)*LCH
    for (int i = LCH - 1; i >= 0; --i) {
      tgs[i] = tag;                              // out[c*LCH+i] = tag_{c*LCH+i+1}
      tag = (int)((bp[i] >> (4 * tag)) & 15ULL);
    }
  }
  __syncthreads();
  dout[1 + c * LCH + t] = (float)tgs[t];
}

// ---------------- launcher ----------------
extern "C" void kernel_launch(void* const* d_in, const int* in_sizes, int n_in,
                              void* d_out, int out_size, void* d_ws, size_t ws_size,
                              hipStream_t stream) {
  const int*   sent = (const int*)d_in[0];
  const float* emb  = (const float*)d_in[1];
  const float* wihf = (const float*)d_in[2];
  const float* whhf = (const float*)d_in[3];
  const float* bf   = (const float*)d_in[4];
  const float* wihb = (const float*)d_in[5];
  const float* whhb = (const float*)d_in[6];
  const float* bb   = (const float*)d_in[7];
  const float* h0   = (const float*)d_in[8];
  const float* c0   = (const float*)d_in[9];
  const float* Wout = (const float*)d_in[10];
  const float* bout = (const float*)d_in[11];
  const float* trans= (const float*)d_in[12];
  float* out = (float*)d_out;
  char* ws = (char*)d_ws;
  if (ws_size < WS_NEED) return;  // workspace too small: bail (visible as wrong output)

  float* xs    = (float*)(ws + OFF_XS);
  float* wT    = (float*)(ws + OFF_WT);
  float* xpf   = (float*)(ws + OFF_XPF);
  float* xpb   = (float*)(ws + OFF_XPB);
  float* hf    = (float*)(ws + OFF_HF);
  float* hb    = (float*)(ws + OFF_HB);
  float* feats = (float*)(ws + OFF_FEATS);
  float* pmat  = (float*)(ws + OFF_PMAT);
  float* fvin  = (float*)(ws + OFF_FVIN);
  unsigned long long* bptr = (unsigned long long*)(ws + OFF_BPTR);
  int*   cmap  = (int*)(ws + OFF_CMAP);
  int*   evec  = (int*)(ws + OFF_EVEC);
  int*   best  = (int*)(ws + OFF_BEST);
  unsigned long long* xhd = (unsigned long long*)(ws + OFF_XHD);  // inside feats region
  unsigned* xtk = (unsigned*)(ws + OFF_XTK);
  unsigned* epoch = (unsigned*)(ws + OFF_EPOCH);

  hipLaunchKernelGGL(k_init, dim3(32), dim3(256), 0, stream, xhd, xtk, epoch);
  hipLaunchKernelGGL(k_gather, dim3(512), dim3(256), 0, stream, sent, emb, xs);
  hipLaunchKernelGGL(k_transpose, dim3(2048), dim3(256), 0, stream, wihf, wihb, wT);
  hipLaunchKernelGGL(k_inproj, dim3(512, 8, 2), dim3(256), 0, stream,
                     xs, wT, bf, bb, xpf, xpb);
  hipLaunchKernelGGL(k_lstm, dim3(256), dim3(512), 0, stream,
                     whhf, whhb, h0, c0, xpf, xpb, hf, hb, xhd, xtk, epoch);
  hipLaunchKernelGGL(k_feats, dim3(64), dim3(256), 0, stream, hf, hb, Wout, bout, feats);
  hipLaunchKernelGGL(k_vit_chunkmat, dim3(NC), dim3(192), 0, stream, feats, trans, pmat);
  hipLaunchKernelGGL(k_vit_scan, dim3(1), dim3(192), 0, stream, pmat, trans, fvin, out, best);
  hipLaunchKernelGGL(k_vit_replay, dim3(NC), dim3(64), 0, stream, feats, trans, fvin, bptr);
  hipLaunchKernelGGL(k_bt_chunk, dim3(NC), dim3(64), 0, stream, bptr, cmap);
  hipLaunchKernelGGL(k_bt_scan, dim3(1), dim3(256), 0, stream, cmap, best, evec);
  hipLaunchKernelGGL(k_bt_replay, dim3(NC), dim3(64), 0, stream, bptr, evec, out);
}

// Round 7
// 25850.772 us; speedup vs baseline: 2.4105x; 2.4105x over previous
//
#include <hip/hip_runtime.h>
#include <cstdint>
#include <cstddef>

// ---------------- problem constants ----------------
namespace {
constexpr int Bb = 8, Ss = 2048, Ee = 256, Hh = 256, G4 = 1024, Tt = 12;
constexpr int NTOK = Bb * Ss;              // 16384 rows
constexpr int NC = 256, LCH = 64;          // viterbi chunking: 256 chunks x 64 steps
constexpr float FNEG = -10000.0f;
constexpr int START_TAG = 10, STOP_TAG = 11;

// ---------------- workspace layout (bytes) ----------------
constexpr size_t OFF_XS    = 0;                         // [16384][256] f32 gathered embeddings
constexpr size_t SZ_XS     = (size_t)NTOK * Ee * 4;
constexpr size_t OFF_WT    = OFF_XS + SZ_XS;            // [2][256][1024] f32 w_ih transposed
constexpr size_t SZ_WT     = (size_t)2 * Ee * G4 * 4;
constexpr size_t OFF_XPF   = OFF_WT + SZ_WT;            // [2048][8][1024] f32 x-proj fwd (bias folded)
constexpr size_t SZ_XP     = (size_t)Ss * Bb * G4 * 4;
constexpr size_t OFF_XPB   = OFF_XPF + SZ_XP;
constexpr size_t OFF_HF    = OFF_XPB + SZ_XP;           // [2048][8][256] f32 fwd hidden history
constexpr size_t SZ_H      = (size_t)Ss * Bb * Hh * 4;
constexpr size_t OFF_HB    = OFF_HF + SZ_H;
constexpr size_t OFF_FEATS = OFF_HB + SZ_H;             // [16384][12] f32
constexpr size_t SZ_FEATS  = (size_t)NTOK * Tt * 4;
constexpr size_t OFF_PMAT  = OFF_FEATS + SZ_FEATS;      // [256][144] f32 chunk max-plus mats
constexpr size_t SZ_PMAT   = (size_t)NC * 144 * 4;
constexpr size_t OFF_FVIN  = OFF_PMAT + SZ_PMAT;        // [256][12] f32 chunk-entry fv
constexpr size_t SZ_FVIN   = (size_t)NC * Tt * 4;
constexpr size_t OFF_BPTR  = OFF_FVIN + SZ_FVIN;        // [16384] u64 packed 12x4bit backptrs
constexpr size_t SZ_BPTR   = (size_t)NTOK * 8;
constexpr size_t OFF_CMAP  = OFF_BPTR + SZ_BPTR;        // [256][12] int chunk composed maps
constexpr size_t SZ_CMAP   = (size_t)NC * Tt * 4;
constexpr size_t OFF_EVEC  = OFF_CMAP + SZ_CMAP;        // [256] int tag at chunk-end
constexpr size_t SZ_EVEC   = (size_t)NC * 4;
constexpr size_t OFF_BEST  = OFF_EVEC + SZ_EVEC;        // [1] int
constexpr size_t SZ_BEST   = 256;
constexpr size_t OFF_HD    = OFF_BEST + SZ_BEST;        // (legacy, unused)
constexpr size_t SZ_HD     = (size_t)2 * 2 * 2048 * 8;
constexpr size_t OFF_EPOCH = OFF_HD + SZ_HD;            // [1] u32 per-run epoch (realtime fold)
constexpr size_t SZ_EPOCH  = 256;
constexpr size_t WS_NEED   = OFF_EPOCH + SZ_EPOCH;      // ~179 MB

// Per-XCD exchange state lives INSIDE the feats region (dead until k_feats):
//   xhd: [8 xcd][2 dir][2 par][2048] u64 tagged h   = 512 KB
//   xtk: [8 xcd] u32 arrival tickets, 128B apart    = 1 KB
//   hsk: [8 xcd][64] u64 handshake tokens           = 4 KB
//   dcs: [8 xcd][32] u64 fast/slow decision         = 2 KB
constexpr size_t OFF_XHD   = OFF_FEATS;
constexpr size_t SZ_XHD    = (size_t)8 * 2 * 2 * 2048 * 8;   // 524288
constexpr size_t OFF_XTK   = OFF_XHD + SZ_XHD;
constexpr size_t SZ_XTK    = 1024;
constexpr size_t OFF_HSK   = OFF_XTK + SZ_XTK;
constexpr size_t SZ_HSK    = (size_t)8 * 64 * 8;             // 4096
constexpr size_t OFF_DCS   = OFF_HSK + SZ_HSK;
constexpr size_t SZ_DCS    = (size_t)8 * 32 * 8;             // 2048
static_assert(OFF_DCS + SZ_DCS - OFF_XHD <= SZ_FEATS,
              "exchange state must fit in feats region");

constexpr int POLL_TMO = 1 << 14;   // step-poll anti-hang valve (dead group exits cleanly)
constexpr int TMO_HS   = 4096;      // handshake token wait
constexpr int TMO_DC   = 1 << 20;   // decision wait (always arrives; valve only)

__device__ __forceinline__ float4 f4fma(float a, float4 b, float4 c) {
  c.x = fmaf(a, b.x, c.x); c.y = fmaf(a, b.y, c.y);
  c.z = fmaf(a, b.z, c.z); c.w = fmaf(a, b.w, c.w);
  return c;
}

// sum across the 4 lanes of a quad via DPP quad_perm -- VALU pipe only.
__device__ __forceinline__ float quad_sum(float x) {
  float y = __int_as_float(
      __builtin_amdgcn_update_dpp(0, __float_as_int(x), 0xB1, 0xF, 0xF, true));
  x += y;  // + lane^1
  y = __int_as_float(
      __builtin_amdgcn_update_dpp(0, __float_as_int(x), 0x4E, 0xF, 0xF, true));
  return x + y;  // + lane^2
}
__device__ __forceinline__ float4 quad_sum4(float4 v) {
  v.x = quad_sum(v.x); v.y = quad_sum(v.y);
  v.z = quad_sum(v.z); v.w = quad_sum(v.w);
  return v;
}

// ---------------- exchange primitives ----------------
// R9/R10 post-mortem: plain-store -> sc0-load has NO reliable within-run
// cross-CU visibility (R10: epoch-salted polls spun >500K iters; R9's speed
// was stale-data acceptance from the previous run). The only primitives
// proven visible cross-CU on this machine are ATOMICS (R5/R7/R8 all
// correct). Atomics execute at the TCC (L2) unless sc1 forces memory-side:
//   FAST pair: flag-free global_atomic ops -> local XCD L2 (coherent for a
//     same-XCD group, ~300cy RT). Bypass L1 entirely.
//   SLOW pair (R7-proven semantics): sc1 atomic swap publish (memory-side)
//     + sc0 sc1 load poll (MALL read) -> coherent across XCDs, ~1us RT.
// A startup handshake measures which regime holds and selects per group.
__device__ __forceinline__ unsigned long long l2a_poll(unsigned long long* p) {
  unsigned long long v, z = 0ULL;
  asm volatile("global_atomic_add_x2 %0, %1, %2, off sc0\n\t"
               "s_waitcnt vmcnt(0)"
               : "=v"(v) : "v"(p), "v"(z) : "memory");
  return v;
}
__device__ __forceinline__ void l2a_pub(unsigned long long* p, unsigned long long v) {
  asm volatile("global_atomic_swap_x2 %0, %1, off"
               :: "v"(p), "v"(v) : "memory");
}
__device__ __forceinline__ unsigned long long mall_poll(unsigned long long* p) {
  unsigned long long v;
  asm volatile("global_load_dwordx2 %0, %1, off sc0 sc1\n\t"
               "s_waitcnt vmcnt(0)"
               : "=v"(v) : "v"(p) : "memory");
  return v;
}
__device__ __forceinline__ void mall_pub(unsigned long long* p, unsigned long long v) {
  asm volatile("global_atomic_swap_x2 %0, %1, off sc1"
               :: "v"(p), "v"(v) : "memory");
}
__device__ __forceinline__ unsigned long long ex_poll(unsigned long long* p, int fastp) {
  return fastp ? l2a_poll(p) : mall_poll(p);
}
__device__ __forceinline__ void ex_pub(unsigned long long* p, unsigned long long v,
                                       int fastp) {
  if (fastp) l2a_pub(p, v); else mall_pub(p, v);
}
}  // namespace

// ---------------- init: zero exchange state; stamp run epoch ----------------
// Runs each launch/graph-replay. Epoch-salted tags (R10) make every stale
// line fail the tag compare regardless of what previous runs left behind.
__global__ __launch_bounds__(256) void k_init(unsigned long long* xhd, unsigned* xtk,
                                              unsigned* epoch, unsigned long long* hsk,
                                              unsigned long long* dcs) {
  int g = blockIdx.x * 256 + threadIdx.x;
  for (int i = g; i < 8 * 8192; i += 32 * 256) xhd[i] = 0ULL;
  if (g < 512) hsk[g] = 0ULL;
  if (g < 256) dcs[g] = 0ULL;
  if (g < 256) xtk[g] = 0u;
  if (g == 0) {
    unsigned long long rt = __builtin_amdgcn_s_memrealtime();
    *epoch = (unsigned)((rt ^ (rt >> 20) ^ (rt >> 40)) & 0xFFFFFu);
  }
}

// ---------------- gather embeddings: xs[r=t*8+b][k] = emb[sentence[b][t]][k] ----------------
__global__ __launch_bounds__(256) void k_gather(const int* __restrict__ sent,
                                                const float* __restrict__ emb,
                                                float* __restrict__ xs) {
  int rr = threadIdx.x >> 3, p = threadIdx.x & 7;
  int r = blockIdx.x * 32 + rr;
  int tg = r >> 3, bg = r & 7;
  int tok = sent[bg * Ss + tg];
  const float4* src = (const float4*)(emb + (size_t)tok * Ee) + p * 8;
  float4* dst = (float4*)(xs + (size_t)r * Ee) + p * 8;
#pragma unroll
  for (int i = 0; i < 8; ++i) dst[i] = src[i];
}

// ---------------- transpose w_ih -> wT[d][k][n] ----------------
__global__ __launch_bounds__(256) void k_transpose(const float* __restrict__ w_f,
                                                   const float* __restrict__ w_b,
                                                   float* __restrict__ wT) {
  int idx = blockIdx.x * 256 + threadIdx.x;
  if (idx >= 2 * Ee * G4) return;
  int d = idx >> 18;
  int rem = idx & 262143;
  int k = rem >> 10, n = rem & 1023;
  const float* w = d ? w_b : w_f;
  wT[idx] = w[n * Ee + k];
}

// ---------------- input projection GEMM: xp[r][n] = xs[r][:] . w_ih[n][:] + bias[n] ----------------
__global__ __launch_bounds__(256) void k_inproj(const float* __restrict__ xs,
                                                const float* __restrict__ wT,
                                                const float* __restrict__ b_f,
                                                const float* __restrict__ b_b,
                                                float* __restrict__ xpf,
                                                float* __restrict__ xpb) {
  const int dir = blockIdx.z;
  const float* wTd = wT + (size_t)dir * (Ee * G4);
  const float* bv = dir ? b_b : b_f;
  float* xp = dir ? xpb : xpf;
  const int rg = threadIdx.x >> 5, cg = threadIdx.x & 31;
  const int rbase = blockIdx.x * 32 + rg * 4;
  const int c0 = blockIdx.y * 128 + cg * 4;
  const float4* ap0 = (const float4*)(xs + (size_t)(rbase + 0) * Ee);
  const float4* ap1 = (const float4*)(xs + (size_t)(rbase + 1) * Ee);
  const float4* ap2 = (const float4*)(xs + (size_t)(rbase + 2) * Ee);
  const float4* ap3 = (const float4*)(xs + (size_t)(rbase + 3) * Ee);
  float4 acc0 = {0,0,0,0}, acc1 = {0,0,0,0}, acc2 = {0,0,0,0}, acc3 = {0,0,0,0};
#pragma unroll 4
  for (int k4 = 0; k4 < 64; ++k4) {
    float4 a0 = ap0[k4], a1 = ap1[k4], a2 = ap2[k4], a3 = ap3[k4];
    const float* wb = wTd + (size_t)(k4 * 4) * G4 + c0;
    float4 b0 = *(const float4*)(wb);
    float4 b1 = *(const float4*)(wb + G4);
    float4 b2 = *(const float4*)(wb + 2 * G4);
    float4 b3 = *(const float4*)(wb + 3 * G4);
    acc0 = f4fma(a0.x, b0, acc0); acc0 = f4fma(a0.y, b1, acc0);
    acc0 = f4fma(a0.z, b2, acc0); acc0 = f4fma(a0.w, b3, acc0);
    acc1 = f4fma(a1.x, b0, acc1); acc1 = f4fma(a1.y, b1, acc1);
    acc1 = f4fma(a1.z, b2, acc1); acc1 = f4fma(a1.w, b3, acc1);
    acc2 = f4fma(a2.x, b0, acc2); acc2 = f4fma(a2.y, b1, acc2);
    acc2 = f4fma(a2.z, b2, acc2); acc2 = f4fma(a2.w, b3, acc2);
    acc3 = f4fma(a3.x, b0, acc3); acc3 = f4fma(a3.y, b1, acc3);
    acc3 = f4fma(a3.z, b2, acc3); acc3 = f4fma(a3.w, b3, acc3);
  }
  float4 bias = *(const float4*)(bv + c0);
  acc0.x += bias.x; acc0.y += bias.y; acc0.z += bias.z; acc0.w += bias.w;
  acc1.x += bias.x; acc1.y += bias.y; acc1.z += bias.z; acc1.w += bias.w;
  acc2.x += bias.x; acc2.y += bias.y; acc2.z += bias.z; acc2.w += bias.w;
  acc3.x += bias.x; acc3.y += bias.y; acc3.z += bias.z; acc3.w += bias.w;
  *(float4*)(xp + (size_t)(rbase + 0) * G4 + c0) = acc0;
  *(float4*)(xp + (size_t)(rbase + 1) * G4 + c0) = acc1;
  *(float4*)(xp + (size_t)(rbase + 2) * G4 + c0) = acc2;
  *(float4*)(xp + (size_t)(rbase + 3) * G4 + c0) = acc3;
}

// ---------------- persistent bidirectional LSTM recurrence ----------------
// R11: same-XCD groups + ALL-ATOMIC exchange with self-tested fast path.
//   - 256 blocks; per-XCD ticket (agent RMW, proven) forms one group of 16
//     WGs per xcc index (roles unique -> buffers never shared; >=1 complete
//     group by pigeonhole; redundant groups write identical hist).
//   - startup handshake: all WGs l2a_pub a salted token; role-0 l2a_polls
//     all 16 (miss -> group not fast-coherent) then latency-pings its own
//     token 16x serially via s_memrealtime (>~480 ticks=4.8us -> atomics
//     are memory-side). Decision broadcast via MALL slot (always coherent).
//   - step exchange = tag-in-data u64 [(epoch20<<12)|step : f32], parity
//     double-buffer, chosen primitive pair. Tags 0xFFE/0xFFF reserved for
//     decision/handshake (steps <= 2048, no collision).
//   - POLL_TMO deaths are clean (exit before writes); survivors complete.
__global__ __launch_bounds__(512, 2) void k_lstm(
    const float* __restrict__ whh_f, const float* __restrict__ whh_b,
    const float* __restrict__ h0, const float* __restrict__ c0,
    const float* __restrict__ xpf, const float* __restrict__ xpb,
    float* __restrict__ hist_f, float* __restrict__ hist_b,
    unsigned long long* xhd, unsigned* xtk, const unsigned* epoch,
    unsigned long long* hsk, unsigned long long* dcs) {
  __shared__ __align__(16) float h_lds[2048];   // [k][b]
  __shared__ float part[128 * 33];              // [row][ks_hi*8 + b], pad 33
  __shared__ int s_role, s_xcc, wg_dead, s_fast;
  __shared__ unsigned s_ep;

  const int t = threadIdx.x;
  if (t == 0) {
    unsigned xcc = __builtin_amdgcn_s_getreg((3 << 11) | 20) & 7u;  // hwreg(XCC_ID=20,0,4)
    unsigned r = __hip_atomic_fetch_add(xtk + xcc * 32, 1u,
                                        __ATOMIC_RELAXED, __HIP_MEMORY_SCOPE_AGENT);
    s_role = (int)r;
    s_xcc = (int)xcc;
    wg_dead = 0;
    s_ep = __hip_atomic_load(epoch, __ATOMIC_RELAXED, __HIP_MEMORY_SCOPE_AGENT);
  }
  __syncthreads();
  if (s_role >= 16) return;   // uniform block exit
  const int wg = s_role, dir = wg >> 3, j0 = (wg & 7) * 32;
  const int xcc = s_xcc;
  const unsigned epbase = s_ep << 12;           // step tags: epbase|s, s<=2048
  const unsigned hstag = epbase | 0xFFFu;
  const unsigned dctag = epbase | 0xFFEu;
  const float* whh = dir ? whh_b : whh_f;
  const float* xp = dir ? xpb : xpf;
  float* hist = dir ? hist_b : hist_f;
  unsigned long long* hd = xhd + (size_t)xcc * 8192 + (size_t)dir * 4096;
  unsigned long long* myhsk = hsk + (size_t)xcc * 64;
  unsigned long long* mydcs = dcs + (size_t)xcc * 32;

  // publish handshake token EARLY (overlaps weight load below)
  if (t == 0)
    l2a_pub(myhsk + wg, ((unsigned long long)hstag << 32) | (unsigned)(wg * 2));

  // FMA-thread mapping: lane = rg(16) x ks_lo(4); wave = ks_hi(4) x bs(2)
  const int wave = t >> 6, lane = t & 63;
  const int ks_hi = wave & 3, bs = wave >> 2;   // wave-uniform
  const int rg = lane >> 2, ks_lo = lane & 3;   // per-lane
  // weights: 8 rows x 16 k per thread, k = ks_hi*64 + i*4 + ks_lo
  float wreg[8][16];
#pragma unroll
  for (int r = 0; r < 8; ++r) {
    const int row = rg * 8 + r;
    const int n = ((row >> 5) << 8) + j0 + (row & 31);
    const float* wb = whh + (size_t)n * Hh + ks_hi * 64 + ks_lo;
#pragma unroll
    for (int i = 0; i < 16; ++i) wreg[r][i] = wb[i * 4];
  }
  // gate-thread mapping (t<256): owns hidden unit (j0+jj, batch bg)
  const int jj = t >> 3, bg = t & 7;
  float c_reg = 0.0f;
  if (t < 256) c_reg = c0[dir * 2048 + bg * Hh + j0 + jj];

  // ---- handshake: decide fast (L2-local) vs slow (MALL) exchange ----
  if (t == 0) {
    if (wg == 0) {
      int to = 0, allseen = 1;
      for (int w = 0; w < 16; ++w) {
        unsigned long long v = l2a_poll(myhsk + w);
        while ((unsigned)(v >> 32) != hstag && to < TMO_HS) {
          ++to; __builtin_amdgcn_s_sleep(1);
          v = l2a_poll(myhsk + w);
        }
        if ((unsigned)(v >> 32) != hstag) { allseen = 0; break; }
      }
      int fastok = 0;
      if (allseen) {
        unsigned long long r0 = __builtin_amdgcn_s_memrealtime();
        unsigned long long acc = 0;
        for (int i = 0; i < 16; ++i)
          acc += l2a_poll(myhsk + (int)(acc & 1ULL));   // serial dep chain
        unsigned long long r1 = __builtin_amdgcn_s_memrealtime();
        fastok = (r1 - r0) < 480ULL;                    // 100MHz ticks: <4.8us
        if (acc == 0xD15EA5EDULL) fastok = 0;           // keep acc live
      }
      mall_pub(mydcs, ((unsigned long long)dctag << 32) | (unsigned)fastok);
      s_fast = fastok;
    } else {
      unsigned long long v = mall_poll(mydcs);
      int to = 0;
      while ((unsigned)(v >> 32) != dctag && to < TMO_DC) {
        ++to; __builtin_amdgcn_s_sleep(4);
        v = mall_poll(mydcs);
      }
      s_fast = ((unsigned)(v >> 32) == dctag) ? (int)(v & 1ULL) : 0;
    }
  }
  __syncthreads();
  const int fastp = s_fast;

  for (int s = 0; s < Ss; ++s) {
    const int tg = dir ? (Ss - 1 - s) : s;
    // gate threads prefetch their 4 x-proj values (overlap the wait)
    float xq0 = 0.f, xq1 = 0.f, xq2 = 0.f, xq3 = 0.f;
    if (t < 256) {
      const float* xpt = xp + (size_t)tg * 8192 + bg * G4 + j0 + jj;
      xq0 = xpt[0]; xq1 = xpt[256]; xq2 = xpt[512]; xq3 = xpt[768];
    }
    // fill h_lds[k][b] with h_{s-1}
    if (s == 0) {
#pragma unroll
      for (int i = 0; i < 4; ++i) {
        int idx = t * 4 + i;
        h_lds[idx] = h0[dir * 2048 + (idx & 7) * Hh + (idx >> 3)];
      }
    } else {
      // poll own 4 tagged words until tag == epbase|s
      unsigned long long* buf = hd + (size_t)((s - 1) & 1) * 2048 + 4 * t;
      const unsigned want = epbase | (unsigned)s;
      int to = 0;
      unsigned long long w0, w1, w2, w3;
      w0 = ex_poll(buf + 0, fastp);
      while ((unsigned)(w0 >> 32) != want && ++to < POLL_TMO) {
        __builtin_amdgcn_s_sleep(1);
        w0 = ex_poll(buf + 0, fastp);
      }
      w1 = ex_poll(buf + 1, fastp);
      while ((unsigned)(w1 >> 32) != want && ++to < POLL_TMO) {
        __builtin_amdgcn_s_sleep(1);
        w1 = ex_poll(buf + 1, fastp);
      }
      w2 = ex_poll(buf + 2, fastp);
      while ((unsigned)(w2 >> 32) != want && ++to < POLL_TMO) {
        __builtin_amdgcn_s_sleep(1);
        w2 = ex_poll(buf + 2, fastp);
      }
      w3 = ex_poll(buf + 3, fastp);
      while ((unsigned)(w3 >> 32) != want && ++to < POLL_TMO) {
        __builtin_amdgcn_s_sleep(1);
        w3 = ex_poll(buf + 3, fastp);
      }
      if (to >= POLL_TMO) wg_dead = 1;
      float4 hv4;
      hv4.x = __uint_as_float((unsigned)w0);
      hv4.y = __uint_as_float((unsigned)w1);
      hv4.z = __uint_as_float((unsigned)w2);
      hv4.w = __uint_as_float((unsigned)w3);
      ((float4*)h_lds)[t] = hv4;
    }
    __syncthreads();  // B1: h_lds ready, prev-step part[] reusable
    if (wg_dead) return;  // dead group: exit before writing anything this step
    // recurrent GEMM: 8 rows x 16 k x 4 b per thread
    float4 acc0 = {0,0,0,0}, acc1 = {0,0,0,0}, acc2 = {0,0,0,0}, acc3 = {0,0,0,0};
    float4 acc4 = {0,0,0,0}, acc5 = {0,0,0,0}, acc6 = {0,0,0,0}, acc7 = {0,0,0,0};
    const float* hbase = h_lds + ks_hi * 512 + ks_lo * 8 + bs * 4;
#pragma unroll
    for (int i = 0; i < 16; ++i) {
      float4 h4 = *(const float4*)(hbase + i * 32);
      acc0 = f4fma(wreg[0][i], h4, acc0);
      acc1 = f4fma(wreg[1][i], h4, acc1);
      acc2 = f4fma(wreg[2][i], h4, acc2);
      acc3 = f4fma(wreg[3][i], h4, acc3);
      acc4 = f4fma(wreg[4][i], h4, acc4);
      acc5 = f4fma(wreg[5][i], h4, acc5);
      acc6 = f4fma(wreg[6][i], h4, acc6);
      acc7 = f4fma(wreg[7][i], h4, acc7);
    }
    // full quad sums in every lane (VALU pipe)
    acc0 = quad_sum4(acc0); acc1 = quad_sum4(acc1);
    acc2 = quad_sum4(acc2); acc3 = quad_sum4(acc3);
    acc4 = quad_sum4(acc4); acc5 = quad_sum4(acc5);
    acc6 = quad_sum4(acc6); acc7 = quad_sum4(acc7);
    // lane ks_lo=q emits rows 2q,2q+1 -- CONSTANT-index cndmask select
    float4 s0 = acc0, s1 = acc1;
    if (ks_lo == 1) { s0 = acc2; s1 = acc3; }
    if (ks_lo == 2) { s0 = acc4; s1 = acc5; }
    if (ks_lo == 3) { s0 = acc6; s1 = acc7; }
    {
      const int row0 = rg * 8 + 2 * ks_lo;
      *(float4*)&part[row0 * 33 + ks_hi * 8 + bs * 4] = s0;
      *(float4*)&part[(row0 + 1) * 33 + ks_hi * 8 + bs * 4] = s1;
    }
    __syncthreads();  // B2: part[] complete
    // fused ks_hi-reduce + gates (PyTorch order i,f,g,o) + publish + hist
    if (t < 256) {
      float z0 = xq0, z1 = xq1, z2 = xq2, z3 = xq3;
#pragma unroll
      for (int kq = 0; kq < 4; ++kq) {
        z0 += part[(jj) * 33 + kq * 8 + bg];
        z1 += part[(32 + jj) * 33 + kq * 8 + bg];
        z2 += part[(64 + jj) * 33 + kq * 8 + bg];
        z3 += part[(96 + jj) * 33 + kq * 8 + bg];
      }
      float iv = 1.0f / (1.0f + expf(-z0));
      float fv = 1.0f / (1.0f + expf(-z1));
      float gv = tanhf(z2);
      float ov = 1.0f / (1.0f + expf(-z3));
      c_reg = fv * c_reg + iv * gv;
      float hv = ov * tanhf(c_reg);
      // publish tagged word: [epbase|(s+1) : h bits], slot = channel*8 + batch
      unsigned long long wv =
          ((unsigned long long)(epbase | (unsigned)(s + 1)) << 32) |
          (unsigned long long)__float_as_uint(hv);
      unsigned long long* bufw = hd + (size_t)(s & 1) * 2048;
      ex_pub(bufw + (size_t)(j0 + jj) * 8 + bg, wv, fastp);
      hist[(size_t)tg * 2048 + bg * Hh + j0 + jj] = hv;
    }
    // no publish-side drain: readers detect tags via atomic polls
  }
}

// ---------------- feats = [hf|hb] @ W_out^T + b_out ----------------
__global__ __launch_bounds__(256) void k_feats(const float* __restrict__ hist_f,
                                               const float* __restrict__ hist_b,
                                               const float* __restrict__ Wout,
                                               const float* __restrict__ bout,
                                               float* __restrict__ feats) {
  __shared__ float wsh[Tt * 512];
  __shared__ float bsh[Tt];
  for (int i = threadIdx.x; i < Tt * 512; i += 256) wsh[i] = Wout[i];
  if (threadIdx.x < Tt) bsh[threadIdx.x] = bout[threadIdx.x];
  __syncthreads();
  int r = blockIdx.x * 256 + threadIdx.x;
  int bq = r >> 11, sq = r & 2047;
  const float4* hf4 = (const float4*)(hist_f + (size_t)sq * 2048 + bq * Hh);
  const float4* hb4 = (const float4*)(hist_b + (size_t)sq * 2048 + bq * Hh);
  float acc[Tt];
#pragma unroll
  for (int j = 0; j < Tt; ++j) acc[j] = bsh[j];
  for (int k4 = 0; k4 < 64; ++k4) {
    float4 x = hf4[k4];
#pragma unroll
    for (int j = 0; j < Tt; ++j) {
      float4 w = *(const float4*)&wsh[j * 512 + k4 * 4];
      acc[j] = fmaf(x.x, w.x, fmaf(x.y, w.y, fmaf(x.z, w.z, fmaf(x.w, w.w, acc[j]))));
    }
  }
  for (int k4 = 0; k4 < 64; ++k4) {
    float4 x = hb4[k4];
#pragma unroll
    for (int j = 0; j < Tt; ++j) {
      float4 w = *(const float4*)&wsh[j * 512 + 256 + k4 * 4];
      acc[j] = fmaf(x.x, w.x, fmaf(x.y, w.y, fmaf(x.z, w.z, fmaf(x.w, w.w, acc[j]))));
    }
  }
#pragma unroll
  for (int j = 0; j < Tt; ++j) feats[(size_t)r * Tt + j] = acc[j];
}

// ---------------- Viterbi phase 1: per-chunk max-plus matrix product ----------------
__global__ __launch_bounds__(192) void k_vit_chunkmat(const float* __restrict__ feats,
                                                      const float* __restrict__ trans,
                                                      float* __restrict__ pmat) {
  __shared__ float R[2][144];
  __shared__ float fe[LCH * Tt];
  __shared__ float ts[144];
  const int t = threadIdx.x, c = blockIdx.x;
  for (int i = t; i < LCH * Tt; i += 192) fe[i] = feats[(size_t)c * LCH * Tt + i];
  if (t < 144) ts[t] = trans[t];
  __syncthreads();
  int j = 0, k = 0;
  float trow[12];
  if (t < 144) {
    j = t / 12; k = t - j * 12;
#pragma unroll
    for (int m = 0; m < 12; ++m) trow[m] = ts[j * 12 + m];
    R[0][t] = ts[t] + fe[j];  // A_{t0}
  }
  __syncthreads();
  for (int i = 1; i < LCH; ++i) {
    int p = (i - 1) & 1;
    if (t < 144) {
      float m = trow[0] + R[p][k];
#pragma unroll
      for (int mm = 1; mm < 12; ++mm) m = fmaxf(m, trow[mm] + R[p][mm * 12 + k]);
      R[p ^ 1][t] = m + fe[i * 12 + j];
    }
    __syncthreads();
  }
  if (t < 144) pmat[(size_t)c * 144 + t] = R[(LCH - 1) & 1][t];
}

// ---------------- Viterbi phase 2: sequential scan over chunk matrices ----------------
__global__ __launch_bounds__(192) void k_vit_scan(const float* __restrict__ pmat,
                                                  const float* __restrict__ trans,
                                                  float* __restrict__ fvin,
                                                  float* __restrict__ dout,
                                                  int* __restrict__ best) {
  __shared__ float fv[12];
  __shared__ float sl[144];
  __shared__ float term[12];
  const int t = threadIdx.x;
  const int j = t / 12, k = t - j * 12;
  if (t < 12) fv[t] = (t == START_TAG) ? 0.0f : FNEG;
  float pv = (t < 144) ? pmat[t] : 0.0f;
  __syncthreads();
  for (int c = 0; c < NC; ++c) {
    if (t < 12) fvin[c * 12 + t] = fv[t];
    float pnext = (t < 144 && c + 1 < NC) ? pmat[(size_t)(c + 1) * 144 + t] : 0.0f;
    if (t < 144) sl[t] = pv + fv[k];
    __syncthreads();
    if (t < 12) {
      float m = sl[t * 12];
#pragma unroll
      for (int kk = 1; kk < 12; ++kk) m = fmaxf(m, sl[t * 12 + kk]);
      fv[t] = m;
    }
    __syncthreads();
    pv = pnext;
  }
  if (t < 12) term[t] = fv[t] + trans[STOP_TAG * 12 + t];
  __syncthreads();
  if (t == 0) {
    float m = term[0]; int a = 0;
    for (int q = 1; q < 12; ++q) { if (term[q] > m) { m = term[q]; a = q; } }
    dout[0] = m;
    best[0] = a;
  }
}

// ---------------- Viterbi phase 3: replay chunks -> packed backpointers ----------------
__global__ __launch_bounds__(64) void k_vit_replay(const float* __restrict__ feats,
                                                   const float* __restrict__ trans,
                                                   const float* __restrict__ fvin,
                                                   unsigned long long* __restrict__ bptr) {
  __shared__ float fe[LCH * Tt];
  __shared__ float fv[12];
  __shared__ int bpn[12];
  const int t = threadIdx.x, c = blockIdx.x;
  for (int i = t; i < LCH * Tt; i += 64) fe[i] = feats[(size_t)c * LCH * Tt + i];
  float trow[12];
  if (t < 12) {
#pragma unroll
    for (int m = 0; m < 12; ++m) trow[m] = trans[t * 12 + m];
    fv[t] = fvin[c * 12 + t];
  }
  __syncthreads();
  for (int i = 0; i < LCH; ++i) {
    float nm = 0.0f;
    if (t < 12) {
      float m = fv[0] + trow[0]; int a = 0;
#pragma unroll
      for (int k = 1; k < 12; ++k) {
        float v = fv[k] + trow[k];
        if (v > m) { m = v; a = k; }   // first-max wins, matches jnp.argmax
      }
      nm = m + fe[i * 12 + t];
      bpn[t] = a;
    }
    __syncthreads();
    if (t < 12) fv[t] = nm;
    if (t == 0) {
      unsigned long long bp = 0;
#pragma unroll
      for (int jq = 0; jq < 12; ++jq)
        bp |= (unsigned long long)(unsigned)bpn[jq] << (4 * jq);
      bptr[(size_t)c * LCH + i] = bp;
    }
    __syncthreads();
  }
}

// ---------------- backtrace phase A: compose per-chunk tag maps ----------------
__global__ __launch_bounds__(64) void k_bt_chunk(const unsigned long long* __restrict__ bptr,
                                                 int* __restrict__ cmap) {
  __shared__ unsigned long long bp[LCH];
  const int t = threadIdx.x, c = blockIdx.x;
  if (t < LCH) bp[t] = bptr[(size_t)c * LCH + t];
  __syncthreads();
  if (t < 12) {
    int v = t;
    for (int i = LCH - 1; i >= 0; --i) v = (int)((bp[i] >> (4 * v)) & 15ULL);
    cmap[c * 12 + t] = v;
  }
}

// ---------------- backtrace phase B: scan chunk maps ----------------
__global__ __launch_bounds__(256) void k_bt_scan(const int* __restrict__ cmap,
                                                 const int* __restrict__ best,
                                                 int* __restrict__ evec) {
  __shared__ int cm[NC * 12];
  __shared__ int es[NC];
  const int t = threadIdx.x;
  for (int i = t; i < NC * 12; i += 256) cm[i] = cmap[i];
  __syncthreads();
  if (t == 0) {
    int tag = best[0];
    es[NC - 1] = tag;
    for (int c = NC - 1; c >= 1; --c) { tag = cm[c * 12 + tag]; es[c - 1] = tag; }
  }
  __syncthreads();
  evec[t] = es[t];
}

// ---------------- backtrace phase C: emit path ----------------
__global__ __launch_bounds__(64) void k_bt_replay(const unsigned long long* __restrict__ bptr,
                                                  const int* __restrict__ evec,
                                                  float* __restrict__ dout) {
  __shared__ unsigned long long bp[LCH];
  __shared__ int tgs[LCH];
  const int t = threadIdx.x, c = blockIdx.x;
  if (t < LCH) bp[t] = bptr[(size_t)c * LCH + t];
  __syncthreads();
  if (t == 0) {
    int tag = evec[c];  // tag at global index (c+1)*LCH
    for (int i = LCH - 1; i >= 0; --i) {
      tgs[i] = tag;                              // out[c*LCH+i] = tag_{c*LCH+i+1}
      tag = (int)((bp[i] >> (4 * tag)) & 15ULL);
    }
  }
  __syncthreads();
  dout[1 + c * LCH + t] = (float)tgs[t];
}

// ---------------- launcher ----------------
extern "C" void kernel_launch(void* const* d_in, const int* in_sizes, int n_in,
                              void* d_out, int out_size, void* d_ws, size_t ws_size,
                              hipStream_t stream) {
  const int*   sent = (const int*)d_in[0];
  const float* emb  = (const float*)d_in[1];
  const float* wihf = (const float*)d_in[2];
  const float* whhf = (const float*)d_in[3];
  const float* bf   = (const float*)d_in[4];
  const float* wihb = (const float*)d_in[5];
  const float* whhb = (const float*)d_in[6];
  const float* bb   = (const float*)d_in[7];
  const float* h0   = (const float*)d_in[8];
  const float* c0   = (const float*)d_in[9];
  const float* Wout = (const float*)d_in[10];
  const float* bout = (const float*)d_in[11];
  const float* trans= (const float*)d_in[12];
  float* out = (float*)d_out;
  char* ws = (char*)d_ws;
  if (ws_size < WS_NEED) return;  // workspace too small: bail (visible as wrong output)

  float* xs    = (float*)(ws + OFF_XS);
  float* wT    = (float*)(ws + OFF_WT);
  float* xpf   = (float*)(ws + OFF_XPF);
  float* xpb   = (float*)(ws + OFF_XPB);
  float* hf    = (float*)(ws + OFF_HF);
  float* hb    = (float*)(ws + OFF_HB);
  float* feats = (float*)(ws + OFF_FEATS);
  float* pmat  = (float*)(ws + OFF_PMAT);
  float* fvin  = (float*)(ws + OFF_FVIN);
  unsigned long long* bptr = (unsigned long long*)(ws + OFF_BPTR);
  int*   cmap  = (int*)(ws + OFF_CMAP);
  int*   evec  = (int*)(ws + OFF_EVEC);
  int*   best  = (int*)(ws + OFF_BEST);
  unsigned long long* xhd = (unsigned long long*)(ws + OFF_XHD);  // inside feats region
  unsigned* xtk = (unsigned*)(ws + OFF_XTK);
  unsigned long long* hsk = (unsigned long long*)(ws + OFF_HSK);
  unsigned long long* dcs = (unsigned long long*)(ws + OFF_DCS);
  unsigned* epoch = (unsigned*)(ws + OFF_EPOCH);

  hipLaunchKernelGGL(k_init, dim3(32), dim3(256), 0, stream, xhd, xtk, epoch, hsk, dcs);
  hipLaunchKernelGGL(k_gather, dim3(512), dim3(256), 0, stream, sent, emb, xs);
  hipLaunchKernelGGL(k_transpose, dim3(2048), dim3(256), 0, stream, wihf, wihb, wT);
  hipLaunchKernelGGL(k_inproj, dim3(512, 8, 2), dim3(256), 0, stream,
                     xs, wT, bf, bb, xpf, xpb);
  hipLaunchKernelGGL(k_lstm, dim3(256), dim3(512), 0, stream,
                     whhf, whhb, h0, c0, xpf, xpb, hf, hb, xhd, xtk, epoch, hsk, dcs);
  hipLaunchKernelGGL(k_feats, dim3(64), dim3(256), 0, stream, hf, hb, Wout, bout, feats);
  hipLaunchKernelGGL(k_vit_chunkmat, dim3(NC), dim3(192), 0, stream, feats, trans, pmat);
  hipLaunchKernelGGL(k_vit_scan, dim3(1), dim3(192), 0, stream, pmat, trans, fvin, out, best);
  hipLaunchKernelGGL(k_vit_replay, dim3(NC), dim3(64), 0, stream, feats, trans, fvin, bptr);
  hipLaunchKernelGGL(k_bt_chunk, dim3(NC), dim3(64), 0, stream, bptr, cmap);
  hipLaunchKernelGGL(k_bt_scan, dim3(1), dim3(256), 0, stream, cmap, best, evec);
  hipLaunchKernelGGL(k_bt_replay, dim3(NC), dim3(64), 0, stream, bptr, evec, out);
}

// Round 8
// 22608.611 us; speedup vs baseline: 2.7562x; 1.1434x over previous
//
#include <hip/hip_runtime.h>
#include <cstdint>
#include <cstddef>

// ---------------- problem constants ----------------
namespace {
constexpr int Bb = 8, Ss = 2048, Ee = 256, Hh = 256, G4 = 1024, Tt = 12;
constexpr int NTOK = Bb * Ss;              // 16384 rows
constexpr int NC = 256, LCH = 64;          // viterbi chunking: 256 chunks x 64 steps
constexpr float FNEG = -10000.0f;
constexpr int START_TAG = 10, STOP_TAG = 11;

// ---------------- workspace layout (bytes) ----------------
constexpr size_t OFF_XS    = 0;                         // [16384][256] f32 gathered embeddings
constexpr size_t SZ_XS     = (size_t)NTOK * Ee * 4;
constexpr size_t OFF_WT    = OFF_XS + SZ_XS;            // [2][256][1024] f32 w_ih transposed
constexpr size_t SZ_WT     = (size_t)2 * Ee * G4 * 4;
constexpr size_t OFF_XPF   = OFF_WT + SZ_WT;            // [2048][8][1024] f32 x-proj fwd (bias folded)
constexpr size_t SZ_XP     = (size_t)Ss * Bb * G4 * 4;
constexpr size_t OFF_XPB   = OFF_XPF + SZ_XP;
constexpr size_t OFF_HF    = OFF_XPB + SZ_XP;           // [2048][8][256] f32 fwd hidden history
constexpr size_t SZ_H      = (size_t)Ss * Bb * Hh * 4;
constexpr size_t OFF_HB    = OFF_HF + SZ_H;
constexpr size_t OFF_FEATS = OFF_HB + SZ_H;             // [16384][12] f32
constexpr size_t SZ_FEATS  = (size_t)NTOK * Tt * 4;
constexpr size_t OFF_PMAT  = OFF_FEATS + SZ_FEATS;      // [256][144] f32 chunk max-plus mats
constexpr size_t SZ_PMAT   = (size_t)NC * 144 * 4;
constexpr size_t OFF_FVIN  = OFF_PMAT + SZ_PMAT;        // [256][12] f32 chunk-entry fv
constexpr size_t SZ_FVIN   = (size_t)NC * Tt * 4;
constexpr size_t OFF_BPTR  = OFF_FVIN + SZ_FVIN;        // [16384] u64 packed 12x4bit backptrs
constexpr size_t SZ_BPTR   = (size_t)NTOK * 8;
constexpr size_t OFF_CMAP  = OFF_BPTR + SZ_BPTR;        // [256][12] int chunk composed maps
constexpr size_t SZ_CMAP   = (size_t)NC * Tt * 4;
constexpr size_t OFF_EVEC  = OFF_CMAP + SZ_CMAP;        // [256] int tag at chunk-end
constexpr size_t SZ_EVEC   = (size_t)NC * 4;
constexpr size_t OFF_BEST  = OFF_EVEC + SZ_EVEC;        // [1] int
constexpr size_t SZ_BEST   = 256;
constexpr size_t OFF_HD    = OFF_BEST + SZ_BEST;        // (legacy, unused)
constexpr size_t SZ_HD     = (size_t)2 * 2 * 2048 * 8;
constexpr size_t OFF_EPOCH = OFF_HD + SZ_HD;            // (legacy, unused)
constexpr size_t SZ_EPOCH  = 256;
constexpr size_t WS_NEED   = OFF_EPOCH + SZ_EPOCH;      // ~179 MB (unchanged)

// R12: w_hh^T [2][256][1024] (2 MB) lives in the XS region, which is dead
// after k_inproj consumes xs. Written by a second k_transpose dispatch that
// runs AFTER k_inproj (stream-ordered), read by k_lstm via normal loads
// (kernel-boundary coherence).
constexpr size_t OFF_WHT   = OFF_XS;
static_assert(2 * 256 * 1024 * 4 <= SZ_XS, "whhT fits in xs region");

// k_lstm weight tiers (per 512-thread WG, one WG per (dir,batch) chain):
//   KR rows of W_hh^T in VGPRs  (2 floats/thread/row -> 2*KR VGPRs)
//   KL rows in LDS              (4 KB/row)
//   KS rows streamed from L2    (656 KB/step, L2-resident read-only)
constexpr int KR = 80, KL = 12, KS = 256 - KR - KL;   // 164
static_assert(KR % 4 == 0 && KL % 4 == 0 && KS % 4 == 0, "tiers 4-aligned");

__device__ __forceinline__ float4 f4fma(float a, float4 b, float4 c) {
  c.x = fmaf(a, b.x, c.x); c.y = fmaf(a, b.y, c.y);
  c.z = fmaf(a, b.z, c.z); c.w = fmaf(a, b.w, c.w);
  return c;
}
}  // namespace

// ---------------- gather embeddings: xs[r=t*8+b][k] = emb[sentence[b][t]][k] ----------------
__global__ __launch_bounds__(256) void k_gather(const int* __restrict__ sent,
                                                const float* __restrict__ emb,
                                                float* __restrict__ xs) {
  int rr = threadIdx.x >> 3, p = threadIdx.x & 7;
  int r = blockIdx.x * 32 + rr;
  int tg = r >> 3, bg = r & 7;
  int tok = sent[bg * Ss + tg];
  const float4* src = (const float4*)(emb + (size_t)tok * Ee) + p * 8;
  float4* dst = (float4*)(xs + (size_t)r * Ee) + p * 8;
#pragma unroll
  for (int i = 0; i < 8; ++i) dst[i] = src[i];
}

// ---------------- transpose [1024][256] -> [k][n] (used for w_ih AND w_hh) ----------------
__global__ __launch_bounds__(256) void k_transpose(const float* __restrict__ w_f,
                                                   const float* __restrict__ w_b,
                                                   float* __restrict__ wT) {
  int idx = blockIdx.x * 256 + threadIdx.x;
  if (idx >= 2 * Ee * G4) return;
  int d = idx >> 18;
  int rem = idx & 262143;
  int k = rem >> 10, n = rem & 1023;
  const float* w = d ? w_b : w_f;
  wT[idx] = w[n * Ee + k];
}

// ---------------- input projection GEMM: xp[r][n] = xs[r][:] . w_ih[n][:] + bias[n] ----------------
__global__ __launch_bounds__(256) void k_inproj(const float* __restrict__ xs,
                                                const float* __restrict__ wT,
                                                const float* __restrict__ b_f,
                                                const float* __restrict__ b_b,
                                                float* __restrict__ xpf,
                                                float* __restrict__ xpb) {
  const int dir = blockIdx.z;
  const float* wTd = wT + (size_t)dir * (Ee * G4);
  const float* bv = dir ? b_b : b_f;
  float* xp = dir ? xpb : xpf;
  const int rg = threadIdx.x >> 5, cg = threadIdx.x & 31;
  const int rbase = blockIdx.x * 32 + rg * 4;
  const int c0 = blockIdx.y * 128 + cg * 4;
  const float4* ap0 = (const float4*)(xs + (size_t)(rbase + 0) * Ee);
  const float4* ap1 = (const float4*)(xs + (size_t)(rbase + 1) * Ee);
  const float4* ap2 = (const float4*)(xs + (size_t)(rbase + 2) * Ee);
  const float4* ap3 = (const float4*)(xs + (size_t)(rbase + 3) * Ee);
  float4 acc0 = {0,0,0,0}, acc1 = {0,0,0,0}, acc2 = {0,0,0,0}, acc3 = {0,0,0,0};
#pragma unroll 4
  for (int k4 = 0; k4 < 64; ++k4) {
    float4 a0 = ap0[k4], a1 = ap1[k4], a2 = ap2[k4], a3 = ap3[k4];
    const float* wb = wTd + (size_t)(k4 * 4) * G4 + c0;
    float4 b0 = *(const float4*)(wb);
    float4 b1 = *(const float4*)(wb + G4);
    float4 b2 = *(const float4*)(wb + 2 * G4);
    float4 b3 = *(const float4*)(wb + 3 * G4);
    acc0 = f4fma(a0.x, b0, acc0); acc0 = f4fma(a0.y, b1, acc0);
    acc0 = f4fma(a0.z, b2, acc0); acc0 = f4fma(a0.w, b3, acc0);
    acc1 = f4fma(a1.x, b0, acc1); acc1 = f4fma(a1.y, b1, acc1);
    acc1 = f4fma(a1.z, b2, acc1); acc1 = f4fma(a1.w, b3, acc1);
    acc2 = f4fma(a2.x, b0, acc2); acc2 = f4fma(a2.y, b1, acc2);
    acc2 = f4fma(a2.z, b2, acc2); acc2 = f4fma(a2.w, b3, acc2);
    acc3 = f4fma(a3.x, b0, acc3); acc3 = f4fma(a3.y, b1, acc3);
    acc3 = f4fma(a3.z, b2, acc3); acc3 = f4fma(a3.w, b3, acc3);
  }
  float4 bias = *(const float4*)(bv + c0);
  acc0.x += bias.x; acc0.y += bias.y; acc0.z += bias.z; acc0.w += bias.w;
  acc1.x += bias.x; acc1.y += bias.y; acc1.z += bias.z; acc1.w += bias.w;
  acc2.x += bias.x; acc2.y += bias.y; acc2.z += bias.z; acc2.w += bias.w;
  acc3.x += bias.x; acc3.y += bias.y; acc3.z += bias.z; acc3.w += bias.w;
  *(float4*)(xp + (size_t)(rbase + 0) * G4 + c0) = acc0;
  *(float4*)(xp + (size_t)(rbase + 1) * G4 + c0) = acc1;
  *(float4*)(xp + (size_t)(rbase + 2) * G4 + c0) = acc2;
  *(float4*)(xp + (size_t)(rbase + 3) * G4 + c0) = acc3;
}

// ---------------- persistent bidirectional LSTM: BATCH-SPLIT, NO EXCHANGE ----------------
// R12: R4-R11 established that every cross-WG coherence path on this machine
// bottoms out at ~5-6.5us/step (atomics are memory-side regardless of
// scope/flags; plain-store->sc0-load has no within-run cross-CU visibility).
// But the LSTM recurrence is INDEPENDENT across batch: h_{t,b} depends only
// on h_{t-1,b}. So: 16 WGs, one per (dir, batch) chain, zero inter-WG
// communication. h lives in LDS, c in registers; per-step sync is two
// __syncthreads. The cost moves to bandwidth: each WG needs all of
// W_hh^T [256k][1024n] per step. 3-tier store: KR=80 k-rows in VGPRs
// (float2/thread/row), KL=12 rows in LDS (48 KB), KS=164 rows streamed from
// the XCD L2 (656 KB/step; whhT is read-only and L2-resident). Streamed
// loads are h-independent so they pipeline across the step boundary; the
// serial path is just GEMV-FMA + gates + 2 barriers.
// Thread map: thread t owns output columns n={2t, 2t+1} of z[1024]
// (PyTorch gate order: rows 0-255=i, 256-511=f, 512-767=g, 768-1023=o).
// Gate phase: threads t<256 own channel t: read z[t],z[256+t],z[512+t],
// z[768+t], update c,h; h -> LDS + hist.
__global__ __launch_bounds__(512, 2) void k_lstm(
    const float* __restrict__ whhT,
    const float* __restrict__ h0, const float* __restrict__ c0,
    const float* __restrict__ xpf, const float* __restrict__ xpb,
    float* __restrict__ hist_f, float* __restrict__ hist_b) {
  __shared__ __align__(16) float h_lds[256];
  __shared__ float z_lds[1024];
  __shared__ float wlds[KL][1024];

  const int wg = blockIdx.x, dir = wg >> 3, b = wg & 7;
  const int t = threadIdx.x;
  const float* WT = whhT + (size_t)dir * (256 * 1024);
  const float* xp = dir ? xpb : xpf;
  float* hist = dir ? hist_b : hist_f;
  const int n0 = 2 * t;

  // tier 1: KR rows in registers (float2 per thread per row)
  float2 wreg[KR];
#pragma unroll
  for (int k = 0; k < KR; ++k)
    wreg[k] = *(const float2*)(WT + (size_t)k * 1024 + n0);
  // tier 2: KL rows into LDS
  for (int i = t; i < KL * 1024; i += 512)
    wlds[i >> 10][i & 1023] = WT[(size_t)(KR + (i >> 10)) * 1024 + (i & 1023)];
  // state
  if (t < 256) h_lds[t] = h0[dir * 2048 + b * 256 + t];
  float c_reg = (t < 256) ? c0[dir * 2048 + b * 256 + t] : 0.0f;
  __syncthreads();

  const float* WS = WT + (size_t)(KR + KL) * 1024;  // tier 3: streamed rows

  for (int s = 0; s < Ss; ++s) {
    const int tg = dir ? (Ss - 1 - s) : s;
    // xp prefetch (h-independent)
    float2 acc = *(const float2*)(xp + (size_t)tg * 8192 + b * 1024 + n0);
    // tier 1: registers
#pragma unroll
    for (int k4 = 0; k4 < KR / 4; ++k4) {
      float4 h4 = *(const float4*)&h_lds[k4 * 4];
      acc.x = fmaf(h4.x, wreg[k4 * 4 + 0].x, acc.x);
      acc.y = fmaf(h4.x, wreg[k4 * 4 + 0].y, acc.y);
      acc.x = fmaf(h4.y, wreg[k4 * 4 + 1].x, acc.x);
      acc.y = fmaf(h4.y, wreg[k4 * 4 + 1].y, acc.y);
      acc.x = fmaf(h4.z, wreg[k4 * 4 + 2].x, acc.x);
      acc.y = fmaf(h4.z, wreg[k4 * 4 + 2].y, acc.y);
      acc.x = fmaf(h4.w, wreg[k4 * 4 + 3].x, acc.x);
      acc.y = fmaf(h4.w, wreg[k4 * 4 + 3].y, acc.y);
    }
    // tier 2: LDS
#pragma unroll
    for (int k4 = 0; k4 < KL / 4; ++k4) {
      float4 h4 = *(const float4*)&h_lds[KR + k4 * 4];
      float2 w0 = *(const float2*)&wlds[k4 * 4 + 0][n0];
      float2 w1 = *(const float2*)&wlds[k4 * 4 + 1][n0];
      float2 w2 = *(const float2*)&wlds[k4 * 4 + 2][n0];
      float2 w3 = *(const float2*)&wlds[k4 * 4 + 3][n0];
      acc.x = fmaf(h4.x, w0.x, acc.x); acc.y = fmaf(h4.x, w0.y, acc.y);
      acc.x = fmaf(h4.y, w1.x, acc.x); acc.y = fmaf(h4.y, w1.y, acc.y);
      acc.x = fmaf(h4.z, w2.x, acc.x); acc.y = fmaf(h4.z, w2.y, acc.y);
      acc.x = fmaf(h4.w, w3.x, acc.x); acc.y = fmaf(h4.w, w3.y, acc.y);
    }
    // tier 3: streamed from L2 (bandwidth-bound; loads are h-independent)
#pragma unroll 4
    for (int k4 = 0; k4 < KS / 4; ++k4) {
      const float* wp = WS + (size_t)(k4 * 4) * 1024 + n0;
      float2 w0 = *(const float2*)(wp);
      float2 w1 = *(const float2*)(wp + 1024);
      float2 w2 = *(const float2*)(wp + 2048);
      float2 w3 = *(const float2*)(wp + 3072);
      float4 h4 = *(const float4*)&h_lds[KR + KL + k4 * 4];
      acc.x = fmaf(h4.x, w0.x, acc.x); acc.y = fmaf(h4.x, w0.y, acc.y);
      acc.x = fmaf(h4.y, w1.x, acc.x); acc.y = fmaf(h4.y, w1.y, acc.y);
      acc.x = fmaf(h4.z, w2.x, acc.x); acc.y = fmaf(h4.z, w2.y, acc.y);
      acc.x = fmaf(h4.w, w3.x, acc.x); acc.y = fmaf(h4.w, w3.y, acc.y);
    }
    z_lds[n0] = acc.x;
    z_lds[n0 + 1] = acc.y;
    __syncthreads();  // B1: z complete; all h_lds reads of this step done
    if (t < 256) {
      float zi = z_lds[t], zf = z_lds[256 + t];
      float zg = z_lds[512 + t], zo = z_lds[768 + t];
      float iv = 1.0f / (1.0f + expf(-zi));
      float fv = 1.0f / (1.0f + expf(-zf));
      float gv = tanhf(zg);
      float ov = 1.0f / (1.0f + expf(-zo));
      c_reg = fv * c_reg + iv * gv;
      float hv = ov * tanhf(c_reg);
      h_lds[t] = hv;
      hist[(size_t)tg * 2048 + b * 256 + t] = hv;
    }
    __syncthreads();  // B2: h_{s} ready for next step
  }
}

// ---------------- feats = [hf|hb] @ W_out^T + b_out ----------------
__global__ __launch_bounds__(256) void k_feats(const float* __restrict__ hist_f,
                                               const float* __restrict__ hist_b,
                                               const float* __restrict__ Wout,
                                               const float* __restrict__ bout,
                                               float* __restrict__ feats) {
  __shared__ float wsh[Tt * 512];
  __shared__ float bsh[Tt];
  for (int i = threadIdx.x; i < Tt * 512; i += 256) wsh[i] = Wout[i];
  if (threadIdx.x < Tt) bsh[threadIdx.x] = bout[threadIdx.x];
  __syncthreads();
  int r = blockIdx.x * 256 + threadIdx.x;
  int bq = r >> 11, sq = r & 2047;
  const float4* hf4 = (const float4*)(hist_f + (size_t)sq * 2048 + bq * Hh);
  const float4* hb4 = (const float4*)(hist_b + (size_t)sq * 2048 + bq * Hh);
  float acc[Tt];
#pragma unroll
  for (int j = 0; j < Tt; ++j) acc[j] = bsh[j];
  for (int k4 = 0; k4 < 64; ++k4) {
    float4 x = hf4[k4];
#pragma unroll
    for (int j = 0; j < Tt; ++j) {
      float4 w = *(const float4*)&wsh[j * 512 + k4 * 4];
      acc[j] = fmaf(x.x, w.x, fmaf(x.y, w.y, fmaf(x.z, w.z, fmaf(x.w, w.w, acc[j]))));
    }
  }
  for (int k4 = 0; k4 < 64; ++k4) {
    float4 x = hb4[k4];
#pragma unroll
    for (int j = 0; j < Tt; ++j) {
      float4 w = *(const float4*)&wsh[j * 512 + 256 + k4 * 4];
      acc[j] = fmaf(x.x, w.x, fmaf(x.y, w.y, fmaf(x.z, w.z, fmaf(x.w, w.w, acc[j]))));
    }
  }
#pragma unroll
  for (int j = 0; j < Tt; ++j) feats[(size_t)r * Tt + j] = acc[j];
}

// ---------------- Viterbi phase 1: per-chunk max-plus matrix product ----------------
__global__ __launch_bounds__(192) void k_vit_chunkmat(const float* __restrict__ feats,
                                                      const float* __restrict__ trans,
                                                      float* __restrict__ pmat) {
  __shared__ float R[2][144];
  __shared__ float fe[LCH * Tt];
  __shared__ float ts[144];
  const int t = threadIdx.x, c = blockIdx.x;
  for (int i = t; i < LCH * Tt; i += 192) fe[i] = feats[(size_t)c * LCH * Tt + i];
  if (t < 144) ts[t] = trans[t];
  __syncthreads();
  int j = 0, k = 0;
  float trow[12];
  if (t < 144) {
    j = t / 12; k = t - j * 12;
#pragma unroll
    for (int m = 0; m < 12; ++m) trow[m] = ts[j * 12 + m];
    R[0][t] = ts[t] + fe[j];  // A_{t0}
  }
  __syncthreads();
  for (int i = 1; i < LCH; ++i) {
    int p = (i - 1) & 1;
    if (t < 144) {
      float m = trow[0] + R[p][k];
#pragma unroll
      for (int mm = 1; mm < 12; ++mm) m = fmaxf(m, trow[mm] + R[p][mm * 12 + k]);
      R[p ^ 1][t] = m + fe[i * 12 + j];
    }
    __syncthreads();
  }
  if (t < 144) pmat[(size_t)c * 144 + t] = R[(LCH - 1) & 1][t];
}

// ---------------- Viterbi phase 2: sequential scan over chunk matrices ----------------
__global__ __launch_bounds__(192) void k_vit_scan(const float* __restrict__ pmat,
                                                  const float* __restrict__ trans,
                                                  float* __restrict__ fvin,
                                                  float* __restrict__ dout,
                                                  int* __restrict__ best) {
  __shared__ float fv[12];
  __shared__ float sl[144];
  __shared__ float term[12];
  const int t = threadIdx.x;
  const int j = t / 12, k = t - j * 12;
  if (t < 12) fv[t] = (t == START_TAG) ? 0.0f : FNEG;
  float pv = (t < 144) ? pmat[t] : 0.0f;
  __syncthreads();
  for (int c = 0; c < NC; ++c) {
    if (t < 12) fvin[c * 12 + t] = fv[t];
    float pnext = (t < 144 && c + 1 < NC) ? pmat[(size_t)(c + 1) * 144 + t] : 0.0f;
    if (t < 144) sl[t] = pv + fv[k];
    __syncthreads();
    if (t < 12) {
      float m = sl[t * 12];
#pragma unroll
      for (int kk = 1; kk < 12; ++kk) m = fmaxf(m, sl[t * 12 + kk]);
      fv[t] = m;
    }
    __syncthreads();
    pv = pnext;
  }
  if (t < 12) term[t] = fv[t] + trans[STOP_TAG * 12 + t];
  __syncthreads();
  if (t == 0) {
    float m = term[0]; int a = 0;
    for (int q = 1; q < 12; ++q) { if (term[q] > m) { m = term[q]; a = q; } }
    dout[0] = m;
    best[0] = a;
  }
}

// ---------------- Viterbi phase 3: replay chunks -> packed backpointers ----------------
__global__ __launch_bounds__(64) void k_vit_replay(const float* __restrict__ feats,
                                                   const float* __restrict__ trans,
                                                   const float* __restrict__ fvin,
                                                   unsigned long long* __restrict__ bptr) {
  __shared__ float fe[LCH * Tt];
  __shared__ float fv[12];
  __shared__ int bpn[12];
  const int t = threadIdx.x, c = blockIdx.x;
  for (int i = t; i < LCH * Tt; i += 64) fe[i] = feats[(size_t)c * LCH * Tt + i];
  float trow[12];
  if (t < 12) {
#pragma unroll
    for (int m = 0; m < 12; ++m) trow[m] = trans[t * 12 + m];
    fv[t] = fvin[c * 12 + t];
  }
  __syncthreads();
  for (int i = 0; i < LCH; ++i) {
    float nm = 0.0f;
    if (t < 12) {
      float m = fv[0] + trow[0]; int a = 0;
#pragma unroll
      for (int k = 1; k < 12; ++k) {
        float v = fv[k] + trow[k];
        if (v > m) { m = v; a = k; }   // first-max wins, matches jnp.argmax
      }
      nm = m + fe[i * 12 + t];
      bpn[t] = a;
    }
    __syncthreads();
    if (t < 12) fv[t] = nm;
    if (t == 0) {
      unsigned long long bp = 0;
#pragma unroll
      for (int jq = 0; jq < 12; ++jq)
        bp |= (unsigned long long)(unsigned)bpn[jq] << (4 * jq);
      bptr[(size_t)c * LCH + i] = bp;
    }
    __syncthreads();
  }
}

// ---------------- backtrace phase A: compose per-chunk tag maps ----------------
__global__ __launch_bounds__(64) void k_bt_chunk(const unsigned long long* __restrict__ bptr,
                                                 int* __restrict__ cmap) {
  __shared__ unsigned long long bp[LCH];
  const int t = threadIdx.x, c = blockIdx.x;
  if (t < LCH) bp[t] = bptr[(size_t)c * LCH + t];
  __syncthreads();
  if (t < 12) {
    int v = t;
    for (int i = LCH - 1; i >= 0; --i) v = (int)((bp[i] >> (4 * v)) & 15ULL);
    cmap[c * 12 + t] = v;
  }
}

// ---------------- backtrace phase B: scan chunk maps ----------------
__global__ __launch_bounds__(256) void k_bt_scan(const int* __restrict__ cmap,
                                                 const int* __restrict__ best,
                                                 int* __restrict__ evec) {
  __shared__ int cm[NC * 12];
  __shared__ int es[NC];
  const int t = threadIdx.x;
  for (int i = t; i < NC * 12; i += 256) cm[i] = cmap[i];
  __syncthreads();
  if (t == 0) {
    int tag = best[0];
    es[NC - 1] = tag;
    for (int c = NC - 1; c >= 1; --c) { tag = cm[c * 12 + tag]; es[c - 1] = tag; }
  }
  __syncthreads();
  evec[t] = es[t];
}

// ---------------- backtrace phase C: emit path ----------------
__global__ __launch_bounds__(64) void k_bt_replay(const unsigned long long* __restrict__ bptr,
                                                  const int* __restrict__ evec,
                                                  float* __restrict__ dout) {
  __shared__ unsigned long long bp[LCH];
  __shared__ int tgs[LCH];
  const int t = threadIdx.x, c = blockIdx.x;
  if (t < LCH) bp[t] = bptr[(size_t)c * LCH + t];
  __syncthreads();
  if (t == 0) {
    int tag = evec[c];  // tag at global index (c+1)*LCH
    for (int i = LCH - 1; i >= 0; --i) {
      tgs[i] = tag;                              // out[c*LCH+i] = tag_{c*LCH+i+1}
      tag = (int)((bp[i] >> (4 * tag)) & 15ULL);
    }
  }
  __syncthreads();
  dout[1 + c * LCH + t] = (float)tgs[t];
}

// ---------------- launcher ----------------
extern "C" void kernel_launch(void* const* d_in, const int* in_sizes, int n_in,
                              void* d_out, int out_size, void* d_ws, size_t ws_size,
                              hipStream_t stream) {
  const int*   sent = (const int*)d_in[0];
  const float* emb  = (const float*)d_in[1];
  const float* wihf = (const float*)d_in[2];
  const float* whhf = (const float*)d_in[3];
  const float* bf   = (const float*)d_in[4];
  const float* wihb = (const float*)d_in[5];
  const float* whhb = (const float*)d_in[6];
  const float* bb   = (const float*)d_in[7];
  const float* h0   = (const float*)d_in[8];
  const float* c0   = (const float*)d_in[9];
  const float* Wout = (const float*)d_in[10];
  const float* bout = (const float*)d_in[11];
  const float* trans= (const float*)d_in[12];
  float* out = (float*)d_out;
  char* ws = (char*)d_ws;
  if (ws_size < WS_NEED) return;  // workspace too small: bail (visible as wrong output)

  float* xs    = (float*)(ws + OFF_XS);
  float* wT    = (float*)(ws + OFF_WT);
  float* xpf   = (float*)(ws + OFF_XPF);
  float* xpb   = (float*)(ws + OFF_XPB);
  float* hf    = (float*)(ws + OFF_HF);
  float* hb    = (float*)(ws + OFF_HB);
  float* feats = (float*)(ws + OFF_FEATS);
  float* pmat  = (float*)(ws + OFF_PMAT);
  float* fvin  = (float*)(ws + OFF_FVIN);
  unsigned long long* bptr = (unsigned long long*)(ws + OFF_BPTR);
  int*   cmap  = (int*)(ws + OFF_CMAP);
  int*   evec  = (int*)(ws + OFF_EVEC);
  int*   best  = (int*)(ws + OFF_BEST);
  float* whT   = (float*)(ws + OFF_WHT);   // overlaps xs: written after k_inproj

  hipLaunchKernelGGL(k_gather, dim3(512), dim3(256), 0, stream, sent, emb, xs);
  hipLaunchKernelGGL(k_transpose, dim3(2048), dim3(256), 0, stream, wihf, wihb, wT);
  hipLaunchKernelGGL(k_inproj, dim3(512, 8, 2), dim3(256), 0, stream,
                     xs, wT, bf, bb, xpf, xpb);
  // xs is dead now; transpose w_hh into its region for k_lstm
  hipLaunchKernelGGL(k_transpose, dim3(2048), dim3(256), 0, stream, whhf, whhb, whT);
  hipLaunchKernelGGL(k_lstm, dim3(16), dim3(512), 0, stream,
                     whT, h0, c0, xpf, xpb, hf, hb);
  hipLaunchKernelGGL(k_feats, dim3(64), dim3(256), 0, stream, hf, hb, Wout, bout, feats);
  hipLaunchKernelGGL(k_vit_chunkmat, dim3(NC), dim3(192), 0, stream, feats, trans, pmat);
  hipLaunchKernelGGL(k_vit_scan, dim3(1), dim3(192), 0, stream, pmat, trans, fvin, out, best);
  hipLaunchKernelGGL(k_vit_replay, dim3(NC), dim3(64), 0, stream, feats, trans, fvin, bptr);
  hipLaunchKernelGGL(k_bt_chunk, dim3(NC), dim3(64), 0, stream, bptr, cmap);
  hipLaunchKernelGGL(k_bt_scan, dim3(1), dim3(256), 0, stream, cmap, best, evec);
  hipLaunchKernelGGL(k_bt_replay, dim3(NC), dim3(64), 0, stream, bptr, evec, out);
}

// Round 9
// 19618.958 us; speedup vs baseline: 3.1762x; 1.1524x over previous
//
#include <hip/hip_runtime.h>
#include <cstdint>
#include <cstddef>

// ---------------- problem constants ----------------
namespace {
constexpr int Bb = 8, Ss = 2048, Ee = 256, Hh = 256, G4 = 1024, Tt = 12;
constexpr int NTOK = Bb * Ss;              // 16384 rows
constexpr int NC = 256, LCH = 64;          // viterbi chunking: 256 chunks x 64 steps
constexpr float FNEG = -10000.0f;
constexpr int START_TAG = 10, STOP_TAG = 11;

// ---------------- workspace layout (bytes) ----------------
constexpr size_t OFF_XS    = 0;                         // [16384][256] f32 gathered embeddings
constexpr size_t SZ_XS     = (size_t)NTOK * Ee * 4;
constexpr size_t OFF_WT    = OFF_XS + SZ_XS;            // [2][256][1024] f32 w_ih transposed
constexpr size_t SZ_WT     = (size_t)2 * Ee * G4 * 4;
constexpr size_t OFF_XPF   = OFF_WT + SZ_WT;            // [2048][8][1024] f32 x-proj fwd (bias folded)
constexpr size_t SZ_XP     = (size_t)Ss * Bb * G4 * 4;
constexpr size_t OFF_XPB   = OFF_XPF + SZ_XP;
constexpr size_t OFF_HF    = OFF_XPB + SZ_XP;           // [2048][8][256] f32 fwd hidden history
constexpr size_t SZ_H      = (size_t)Ss * Bb * Hh * 4;
constexpr size_t OFF_HB    = OFF_HF + SZ_H;
constexpr size_t OFF_FEATS = OFF_HB + SZ_H;             // [16384][12] f32
constexpr size_t SZ_FEATS  = (size_t)NTOK * Tt * 4;
constexpr size_t OFF_PMAT  = OFF_FEATS + SZ_FEATS;      // [256][144] f32 chunk max-plus mats
constexpr size_t SZ_PMAT   = (size_t)NC * 144 * 4;
constexpr size_t OFF_FVIN  = OFF_PMAT + SZ_PMAT;        // [256][12] f32 chunk-entry fv
constexpr size_t SZ_FVIN   = (size_t)NC * Tt * 4;
constexpr size_t OFF_BPTR  = OFF_FVIN + SZ_FVIN;        // [16384] u64 packed 12x4bit backptrs
constexpr size_t SZ_BPTR   = (size_t)NTOK * 8;
constexpr size_t OFF_CMAP  = OFF_BPTR + SZ_BPTR;        // [256][12] int chunk composed maps
constexpr size_t SZ_CMAP   = (size_t)NC * Tt * 4;
constexpr size_t OFF_EVEC  = OFF_CMAP + SZ_CMAP;        // [256] int tag at chunk-end
constexpr size_t SZ_EVEC   = (size_t)NC * 4;
constexpr size_t OFF_BEST  = OFF_EVEC + SZ_EVEC;        // [1] int
constexpr size_t SZ_BEST   = 256;
constexpr size_t OFF_HD    = OFF_BEST + SZ_BEST;        // (legacy, unused)
constexpr size_t SZ_HD     = (size_t)2 * 2 * 2048 * 8;
constexpr size_t OFF_EPOCH = OFF_HD + SZ_HD;            // (legacy, unused)
constexpr size_t SZ_EPOCH  = 256;
constexpr size_t WS_NEED   = OFF_EPOCH + SZ_EPOCH;      // ~179 MB (unchanged)

// w_hh^T [2][256][1024] (2 MB) lives in the XS region, which is dead after
// k_inproj consumes xs. Written by a second k_transpose dispatch that runs
// AFTER k_inproj (stream-ordered), read by k_lstm via normal loads.
constexpr size_t OFF_WHT   = OFF_XS;
static_assert(2 * 256 * 1024 * 4 <= SZ_XS, "whhT fits in xs region");

// k_lstm weight tiers (per 512-thread WG, one WG per (dir,batch) chain):
//   KR rows of W_hh^T in VGPRs  (float2/thread/row -> 2*KR VGPRs)
//   KL rows in LDS              (4 KB/row)
//   KS rows streamed from L2    (496 KB/step, L2-resident read-only)
// R13 vs R12: launch_bounds(512,1) -> 256-VGPR budget. R12's (512,2) capped
// VGPRs at 128, so wreg[80] (160 regs) silently spilled -- VGPR_Count=112
// proved the register tier never existed and ~1MB/step flowed through L1
// (10.6us/step at the ~92GB/s L1-path ceiling). KR=96 (192 regs) + KL=36
// (144KB of the 160KB LDS) cuts the per-step stream to 124 rows = 496KB.
constexpr int KR = 96, KL = 36, KS = 256 - KR - KL;   // 124
static_assert(KR % 4 == 0 && KL % 4 == 0 && KS % 4 == 0, "tiers 4-aligned");

__device__ __forceinline__ float4 f4fma(float a, float4 b, float4 c) {
  c.x = fmaf(a, b.x, c.x); c.y = fmaf(a, b.y, c.y);
  c.z = fmaf(a, b.z, c.z); c.w = fmaf(a, b.w, c.w);
  return c;
}
}  // namespace

// ---------------- gather embeddings: xs[r=t*8+b][k] = emb[sentence[b][t]][k] ----------------
__global__ __launch_bounds__(256) void k_gather(const int* __restrict__ sent,
                                                const float* __restrict__ emb,
                                                float* __restrict__ xs) {
  int rr = threadIdx.x >> 3, p = threadIdx.x & 7;
  int r = blockIdx.x * 32 + rr;
  int tg = r >> 3, bg = r & 7;
  int tok = sent[bg * Ss + tg];
  const float4* src = (const float4*)(emb + (size_t)tok * Ee) + p * 8;
  float4* dst = (float4*)(xs + (size_t)r * Ee) + p * 8;
#pragma unroll
  for (int i = 0; i < 8; ++i) dst[i] = src[i];
}

// ---------------- transpose [1024][256] -> [k][n] (used for w_ih AND w_hh) ----------------
__global__ __launch_bounds__(256) void k_transpose(const float* __restrict__ w_f,
                                                   const float* __restrict__ w_b,
                                                   float* __restrict__ wT) {
  int idx = blockIdx.x * 256 + threadIdx.x;
  if (idx >= 2 * Ee * G4) return;
  int d = idx >> 18;
  int rem = idx & 262143;
  int k = rem >> 10, n = rem & 1023;
  const float* w = d ? w_b : w_f;
  wT[idx] = w[n * Ee + k];
}

// ---------------- input projection GEMM: xp[r][n] = xs[r][:] . w_ih[n][:] + bias[n] ----------------
__global__ __launch_bounds__(256) void k_inproj(const float* __restrict__ xs,
                                                const float* __restrict__ wT,
                                                const float* __restrict__ b_f,
                                                const float* __restrict__ b_b,
                                                float* __restrict__ xpf,
                                                float* __restrict__ xpb) {
  const int dir = blockIdx.z;
  const float* wTd = wT + (size_t)dir * (Ee * G4);
  const float* bv = dir ? b_b : b_f;
  float* xp = dir ? xpb : xpf;
  const int rg = threadIdx.x >> 5, cg = threadIdx.x & 31;
  const int rbase = blockIdx.x * 32 + rg * 4;
  const int c0 = blockIdx.y * 128 + cg * 4;
  const float4* ap0 = (const float4*)(xs + (size_t)(rbase + 0) * Ee);
  const float4* ap1 = (const float4*)(xs + (size_t)(rbase + 1) * Ee);
  const float4* ap2 = (const float4*)(xs + (size_t)(rbase + 2) * Ee);
  const float4* ap3 = (const float4*)(xs + (size_t)(rbase + 3) * Ee);
  float4 acc0 = {0,0,0,0}, acc1 = {0,0,0,0}, acc2 = {0,0,0,0}, acc3 = {0,0,0,0};
#pragma unroll 4
  for (int k4 = 0; k4 < 64; ++k4) {
    float4 a0 = ap0[k4], a1 = ap1[k4], a2 = ap2[k4], a3 = ap3[k4];
    const float* wb = wTd + (size_t)(k4 * 4) * G4 + c0;
    float4 b0 = *(const float4*)(wb);
    float4 b1 = *(const float4*)(wb + G4);
    float4 b2 = *(const float4*)(wb + 2 * G4);
    float4 b3 = *(const float4*)(wb + 3 * G4);
    acc0 = f4fma(a0.x, b0, acc0); acc0 = f4fma(a0.y, b1, acc0);
    acc0 = f4fma(a0.z, b2, acc0); acc0 = f4fma(a0.w, b3, acc0);
    acc1 = f4fma(a1.x, b0, acc1); acc1 = f4fma(a1.y, b1, acc1);
    acc1 = f4fma(a1.z, b2, acc1); acc1 = f4fma(a1.w, b3, acc1);
    acc2 = f4fma(a2.x, b0, acc2); acc2 = f4fma(a2.y, b1, acc2);
    acc2 = f4fma(a2.z, b2, acc2); acc2 = f4fma(a2.w, b3, acc2);
    acc3 = f4fma(a3.x, b0, acc3); acc3 = f4fma(a3.y, b1, acc3);
    acc3 = f4fma(a3.z, b2, acc3); acc3 = f4fma(a3.w, b3, acc3);
  }
  float4 bias = *(const float4*)(bv + c0);
  acc0.x += bias.x; acc0.y += bias.y; acc0.z += bias.z; acc0.w += bias.w;
  acc1.x += bias.x; acc1.y += bias.y; acc1.z += bias.z; acc1.w += bias.w;
  acc2.x += bias.x; acc2.y += bias.y; acc2.z += bias.z; acc2.w += bias.w;
  acc3.x += bias.x; acc3.y += bias.y; acc3.z += bias.z; acc3.w += bias.w;
  *(float4*)(xp + (size_t)(rbase + 0) * G4 + c0) = acc0;
  *(float4*)(xp + (size_t)(rbase + 1) * G4 + c0) = acc1;
  *(float4*)(xp + (size_t)(rbase + 2) * G4 + c0) = acc2;
  *(float4*)(xp + (size_t)(rbase + 3) * G4 + c0) = acc3;
}

// ---------------- persistent bidirectional LSTM: BATCH-SPLIT, NO EXCHANGE ----------------
// R12/R13: 16 WGs, one per (dir, batch) chain, ZERO inter-WG communication
// (R4-R11 established all cross-WG coherence paths bottom out at ~5-6.5us/
// step on this machine). h lives in LDS, c in registers; per-step sync is
// two __syncthreads. Weights 3-tiered: VGPR / LDS / L2-stream (see tier
// comment above). Streamed rows are h-independent so they pipeline.
// Thread map: thread t owns output columns n={2t,2t+1} of z[1024] (PyTorch
// gate order: rows 0-255=i, 256-511=f, 512-767=g, 768-1023=o). Gate phase:
// threads t<256 own channel t.
__global__ __launch_bounds__(512, 1) void k_lstm(
    const float* __restrict__ whhT,
    const float* __restrict__ h0, const float* __restrict__ c0,
    const float* __restrict__ xpf, const float* __restrict__ xpb,
    float* __restrict__ hist_f, float* __restrict__ hist_b) {
  __shared__ __align__(16) float h_lds[256];
  __shared__ float z_lds[1024];
  __shared__ float wlds[KL][1024];

  const int wg = blockIdx.x, dir = wg >> 3, b = wg & 7;
  const int t = threadIdx.x;
  const float* WT = whhT + (size_t)dir * (256 * 1024);
  const float* xp = dir ? xpb : xpf;
  float* hist = dir ? hist_b : hist_f;
  const int n0 = 2 * t;

  // tier 1: KR rows in registers (float2 per thread per row)
  float2 wreg[KR];
#pragma unroll
  for (int k = 0; k < KR; ++k)
    wreg[k] = *(const float2*)(WT + (size_t)k * 1024 + n0);
  // tier 2: KL rows into LDS
  for (int i = t; i < KL * 1024; i += 512)
    wlds[i >> 10][i & 1023] = WT[(size_t)(KR + (i >> 10)) * 1024 + (i & 1023)];
  // state
  if (t < 256) h_lds[t] = h0[dir * 2048 + b * 256 + t];
  float c_reg = (t < 256) ? c0[dir * 2048 + b * 256 + t] : 0.0f;
  __syncthreads();

  const float* WS = WT + (size_t)(KR + KL) * 1024;  // tier 3: streamed rows

  for (int s = 0; s < Ss; ++s) {
    const int tg = dir ? (Ss - 1 - s) : s;
    // xp prefetch (h-independent)
    float2 acc = *(const float2*)(xp + (size_t)tg * 8192 + b * 1024 + n0);
    // tier 1: registers
#pragma unroll
    for (int k4 = 0; k4 < KR / 4; ++k4) {
      float4 h4 = *(const float4*)&h_lds[k4 * 4];
      acc.x = fmaf(h4.x, wreg[k4 * 4 + 0].x, acc.x);
      acc.y = fmaf(h4.x, wreg[k4 * 4 + 0].y, acc.y);
      acc.x = fmaf(h4.y, wreg[k4 * 4 + 1].x, acc.x);
      acc.y = fmaf(h4.y, wreg[k4 * 4 + 1].y, acc.y);
      acc.x = fmaf(h4.z, wreg[k4 * 4 + 2].x, acc.x);
      acc.y = fmaf(h4.z, wreg[k4 * 4 + 2].y, acc.y);
      acc.x = fmaf(h4.w, wreg[k4 * 4 + 3].x, acc.x);
      acc.y = fmaf(h4.w, wreg[k4 * 4 + 3].y, acc.y);
    }
    // tier 2: LDS
#pragma unroll
    for (int k4 = 0; k4 < KL / 4; ++k4) {
      float4 h4 = *(const float4*)&h_lds[KR + k4 * 4];
      float2 w0 = *(const float2*)&wlds[k4 * 4 + 0][n0];
      float2 w1 = *(const float2*)&wlds[k4 * 4 + 1][n0];
      float2 w2 = *(const float2*)&wlds[k4 * 4 + 2][n0];
      float2 w3 = *(const float2*)&wlds[k4 * 4 + 3][n0];
      acc.x = fmaf(h4.x, w0.x, acc.x); acc.y = fmaf(h4.x, w0.y, acc.y);
      acc.x = fmaf(h4.y, w1.x, acc.x); acc.y = fmaf(h4.y, w1.y, acc.y);
      acc.x = fmaf(h4.z, w2.x, acc.x); acc.y = fmaf(h4.z, w2.y, acc.y);
      acc.x = fmaf(h4.w, w3.x, acc.x); acc.y = fmaf(h4.w, w3.y, acc.y);
    }
    // tier 3: streamed from L2 (bandwidth-bound; loads are h-independent)
#pragma unroll 4
    for (int k4 = 0; k4 < KS / 4; ++k4) {
      const float* wp = WS + (size_t)(k4 * 4) * 1024 + n0;
      float2 w0 = *(const float2*)(wp);
      float2 w1 = *(const float2*)(wp + 1024);
      float2 w2 = *(const float2*)(wp + 2048);
      float2 w3 = *(const float2*)(wp + 3072);
      float4 h4 = *(const float4*)&h_lds[KR + KL + k4 * 4];
      acc.x = fmaf(h4.x, w0.x, acc.x); acc.y = fmaf(h4.x, w0.y, acc.y);
      acc.x = fmaf(h4.y, w1.x, acc.x); acc.y = fmaf(h4.y, w1.y, acc.y);
      acc.x = fmaf(h4.z, w2.x, acc.x); acc.y = fmaf(h4.z, w2.y, acc.y);
      acc.x = fmaf(h4.w, w3.x, acc.x); acc.y = fmaf(h4.w, w3.y, acc.y);
    }
    z_lds[n0] = acc.x;
    z_lds[n0 + 1] = acc.y;
    __syncthreads();  // B1: z complete; all h_lds reads of this step done
    if (t < 256) {
      float zi = z_lds[t], zf = z_lds[256 + t];
      float zg = z_lds[512 + t], zo = z_lds[768 + t];
      float iv = 1.0f / (1.0f + expf(-zi));
      float fv = 1.0f / (1.0f + expf(-zf));
      float gv = tanhf(zg);
      float ov = 1.0f / (1.0f + expf(-zo));
      c_reg = fv * c_reg + iv * gv;
      float hv = ov * tanhf(c_reg);
      h_lds[t] = hv;
      hist[(size_t)tg * 2048 + b * 256 + t] = hv;
    }
    __syncthreads();  // B2: h_{s} ready for next step
  }
}

// ---------------- feats = [hf|hb] @ W_out^T + b_out ----------------
__global__ __launch_bounds__(256) void k_feats(const float* __restrict__ hist_f,
                                               const float* __restrict__ hist_b,
                                               const float* __restrict__ Wout,
                                               const float* __restrict__ bout,
                                               float* __restrict__ feats) {
  __shared__ float wsh[Tt * 512];
  __shared__ float bsh[Tt];
  for (int i = threadIdx.x; i < Tt * 512; i += 256) wsh[i] = Wout[i];
  if (threadIdx.x < Tt) bsh[threadIdx.x] = bout[threadIdx.x];
  __syncthreads();
  int r = blockIdx.x * 256 + threadIdx.x;
  int bq = r >> 11, sq = r & 2047;
  const float4* hf4 = (const float4*)(hist_f + (size_t)sq * 2048 + bq * Hh);
  const float4* hb4 = (const float4*)(hist_b + (size_t)sq * 2048 + bq * Hh);
  float acc[Tt];
#pragma unroll
  for (int j = 0; j < Tt; ++j) acc[j] = bsh[j];
  for (int k4 = 0; k4 < 64; ++k4) {
    float4 x = hf4[k4];
#pragma unroll
    for (int j = 0; j < Tt; ++j) {
      float4 w = *(const float4*)&wsh[j * 512 + k4 * 4];
      acc[j] = fmaf(x.x, w.x, fmaf(x.y, w.y, fmaf(x.z, w.z, fmaf(x.w, w.w, acc[j]))));
    }
  }
  for (int k4 = 0; k4 < 64; ++k4) {
    float4 x = hb4[k4];
#pragma unroll
    for (int j = 0; j < Tt; ++j) {
      float4 w = *(const float4*)&wsh[j * 512 + 256 + k4 * 4];
      acc[j] = fmaf(x.x, w.x, fmaf(x.y, w.y, fmaf(x.z, w.z, fmaf(x.w, w.w, acc[j]))));
    }
  }
#pragma unroll
  for (int j = 0; j < Tt; ++j) feats[(size_t)r * Tt + j] = acc[j];
}

// ---------------- Viterbi phase 1: per-chunk max-plus matrix product ----------------
__global__ __launch_bounds__(192) void k_vit_chunkmat(const float* __restrict__ feats,
                                                      const float* __restrict__ trans,
                                                      float* __restrict__ pmat) {
  __shared__ float R[2][144];
  __shared__ float fe[LCH * Tt];
  __shared__ float ts[144];
  const int t = threadIdx.x, c = blockIdx.x;
  for (int i = t; i < LCH * Tt; i += 192) fe[i] = feats[(size_t)c * LCH * Tt + i];
  if (t < 144) ts[t] = trans[t];
  __syncthreads();
  int j = 0, k = 0;
  float trow[12];
  if (t < 144) {
    j = t / 12; k = t - j * 12;
#pragma unroll
    for (int m = 0; m < 12; ++m) trow[m] = ts[j * 12 + m];
    R[0][t] = ts[t] + fe[j];  // A_{t0}
  }
  __syncthreads();
  for (int i = 1; i < LCH; ++i) {
    int p = (i - 1) & 1;
    if (t < 144) {
      float m = trow[0] + R[p][k];
#pragma unroll
      for (int mm = 1; mm < 12; ++mm) m = fmaxf(m, trow[mm] + R[p][mm * 12 + k]);
      R[p ^ 1][t] = m + fe[i * 12 + j];
    }
    __syncthreads();
  }
  if (t < 144) pmat[(size_t)c * 144 + t] = R[(LCH - 1) & 1][t];
}

// ---------------- Viterbi phase 2: sequential scan over chunk matrices ----------------
__global__ __launch_bounds__(192) void k_vit_scan(const float* __restrict__ pmat,
                                                  const float* __restrict__ trans,
                                                  float* __restrict__ fvin,
                                                  float* __restrict__ dout,
                                                  int* __restrict__ best) {
  __shared__ float fv[12];
  __shared__ float sl[144];
  __shared__ float term[12];
  const int t = threadIdx.x;
  const int j = t / 12, k = t - j * 12;
  if (t < 12) fv[t] = (t == START_TAG) ? 0.0f : FNEG;
  float pv = (t < 144) ? pmat[t] : 0.0f;
  __syncthreads();
  for (int c = 0; c < NC; ++c) {
    if (t < 12) fvin[c * 12 + t] = fv[t];
    float pnext = (t < 144 && c + 1 < NC) ? pmat[(size_t)(c + 1) * 144 + t] : 0.0f;
    if (t < 144) sl[t] = pv + fv[k];
    __syncthreads();
    if (t < 12) {
      float m = sl[t * 12];
#pragma unroll
      for (int kk = 1; kk < 12; ++kk) m = fmaxf(m, sl[t * 12 + kk]);
      fv[t] = m;
    }
    __syncthreads();
    pv = pnext;
  }
  if (t < 12) term[t] = fv[t] + trans[STOP_TAG * 12 + t];
  __syncthreads();
  if (t == 0) {
    float m = term[0]; int a = 0;
    for (int q = 1; q < 12; ++q) { if (term[q] > m) { m = term[q]; a = q; } }
    dout[0] = m;
    best[0] = a;
  }
}

// ---------------- Viterbi phase 3: replay chunks -> packed backpointers ----------------
__global__ __launch_bounds__(64) void k_vit_replay(const float* __restrict__ feats,
                                                   const float* __restrict__ trans,
                                                   const float* __restrict__ fvin,
                                                   unsigned long long* __restrict__ bptr) {
  __shared__ float fe[LCH * Tt];
  __shared__ float fv[12];
  __shared__ int bpn[12];
  const int t = threadIdx.x, c = blockIdx.x;
  for (int i = t; i < LCH * Tt; i += 64) fe[i] = feats[(size_t)c * LCH * Tt + i];
  float trow[12];
  if (t < 12) {
#pragma unroll
    for (int m = 0; m < 12; ++m) trow[m] = trans[t * 12 + m];
    fv[t] = fvin[c * 12 + t];
  }
  __syncthreads();
  for (int i = 0; i < LCH; ++i) {
    float nm = 0.0f;
    if (t < 12) {
      float m = fv[0] + trow[0]; int a = 0;
#pragma unroll
      for (int k = 1; k < 12; ++k) {
        float v = fv[k] + trow[k];
        if (v > m) { m = v; a = k; }   // first-max wins, matches jnp.argmax
      }
      nm = m + fe[i * 12 + t];
      bpn[t] = a;
    }
    __syncthreads();
    if (t < 12) fv[t] = nm;
    if (t == 0) {
      unsigned long long bp = 0;
#pragma unroll
      for (int jq = 0; jq < 12; ++jq)
        bp |= (unsigned long long)(unsigned)bpn[jq] << (4 * jq);
      bptr[(size_t)c * LCH + i] = bp;
    }
    __syncthreads();
  }
}

// ---------------- backtrace phase A: compose per-chunk tag maps ----------------
__global__ __launch_bounds__(64) void k_bt_chunk(const unsigned long long* __restrict__ bptr,
                                                 int* __restrict__ cmap) {
  __shared__ unsigned long long bp[LCH];
  const int t = threadIdx.x, c = blockIdx.x;
  if (t < LCH) bp[t] = bptr[(size_t)c * LCH + t];
  __syncthreads();
  if (t < 12) {
    int v = t;
    for (int i = LCH - 1; i >= 0; --i) v = (int)((bp[i] >> (4 * v)) & 15ULL);
    cmap[c * 12 + t] = v;
  }
}

// ---------------- backtrace phase B: scan chunk maps ----------------
__global__ __launch_bounds__(256) void k_bt_scan(const int* __restrict__ cmap,
                                                 const int* __restrict__ best,
                                                 int* __restrict__ evec) {
  __shared__ int cm[NC * 12];
  __shared__ int es[NC];
  const int t = threadIdx.x;
  for (int i = t; i < NC * 12; i += 256) cm[i] = cmap[i];
  __syncthreads();
  if (t == 0) {
    int tag = best[0];
    es[NC - 1] = tag;
    for (int c = NC - 1; c >= 1; --c) { tag = cm[c * 12 + tag]; es[c - 1] = tag; }
  }
  __syncthreads();
  evec[t] = es[t];
}

// ---------------- backtrace phase C: emit path ----------------
__global__ __launch_bounds__(64) void k_bt_replay(const unsigned long long* __restrict__ bptr,
                                                  const int* __restrict__ evec,
                                                  float* __restrict__ dout) {
  __shared__ unsigned long long bp[LCH];
  __shared__ int tgs[LCH];
  const int t = threadIdx.x, c = blockIdx.x;
  if (t < LCH) bp[t] = bptr[(size_t)c * LCH + t];
  __syncthreads();
  if (t == 0) {
    int tag = evec[c];  // tag at global index (c+1)*LCH
    for (int i = LCH - 1; i >= 0; --i) {
      tgs[i] = tag;                              // out[c*LCH+i] = tag_{c*LCH+i+1}
      tag = (int)((bp[i] >> (4 * tag)) & 15ULL);
    }
  }
  __syncthreads();
  dout[1 + c * LCH + t] = (float)tgs[t];
}

// ---------------- launcher ----------------
extern "C" void kernel_launch(void* const* d_in, const int* in_sizes, int n_in,
                              void* d_out, int out_size, void* d_ws, size_t ws_size,
                              hipStream_t stream) {
  const int*   sent = (const int*)d_in[0];
  const float* emb  = (const float*)d_in[1];
  const float* wihf = (const float*)d_in[2];
  const float* whhf = (const float*)d_in[3];
  const float* bf   = (const float*)d_in[4];
  const float* wihb = (const float*)d_in[5];
  const float* whhb = (const float*)d_in[6];
  const float* bb   = (const float*)d_in[7];
  const float* h0   = (const float*)d_in[8];
  const float* c0   = (const float*)d_in[9];
  const float* Wout = (const float*)d_in[10];
  const float* bout = (const float*)d_in[11];
  const float* trans= (const float*)d_in[12];
  float* out = (float*)d_out;
  char* ws = (char*)d_ws;
  if (ws_size < WS_NEED) return;  // workspace too small: bail (visible as wrong output)

  float* xs    = (float*)(ws + OFF_XS);
  float* wT    = (float*)(ws + OFF_WT);
  float* xpf   = (float*)(ws + OFF_XPF);
  float* xpb   = (float*)(ws + OFF_XPB);
  float* hf    = (float*)(ws + OFF_HF);
  float* hb    = (float*)(ws + OFF_HB);
  float* feats = (float*)(ws + OFF_FEATS);
  float* pmat  = (float*)(ws + OFF_PMAT);
  float* fvin  = (float*)(ws + OFF_FVIN);
  unsigned long long* bptr = (unsigned long long*)(ws + OFF_BPTR);
  int*   cmap  = (int*)(ws + OFF_CMAP);
  int*   evec  = (int*)(ws + OFF_EVEC);
  int*   best  = (int*)(ws + OFF_BEST);
  float* whT   = (float*)(ws + OFF_WHT);   // overlaps xs: written after k_inproj

  hipLaunchKernelGGL(k_gather, dim3(512), dim3(256), 0, stream, sent, emb, xs);
  hipLaunchKernelGGL(k_transpose, dim3(2048), dim3(256), 0, stream, wihf, wihb, wT);
  hipLaunchKernelGGL(k_inproj, dim3(512, 8, 2), dim3(256), 0, stream,
                     xs, wT, bf, bb, xpf, xpb);
  // xs is dead now; transpose w_hh into its region for k_lstm
  hipLaunchKernelGGL(k_transpose, dim3(2048), dim3(256), 0, stream, whhf, whhb, whT);
  hipLaunchKernelGGL(k_lstm, dim3(16), dim3(512), 0, stream,
                     whT, h0, c0, xpf, xpb, hf, hb);
  hipLaunchKernelGGL(k_feats, dim3(64), dim3(256), 0, stream, hf, hb, Wout, bout, feats);
  hipLaunchKernelGGL(k_vit_chunkmat, dim3(NC), dim3(192), 0, stream, feats, trans, pmat);
  hipLaunchKernelGGL(k_vit_scan, dim3(1), dim3(192), 0, stream, pmat, trans, fvin, out, best);
  hipLaunchKernelGGL(k_vit_replay, dim3(NC), dim3(64), 0, stream, feats, trans, fvin, bptr);
  hipLaunchKernelGGL(k_bt_chunk, dim3(NC), dim3(64), 0, stream, bptr, cmap);
  hipLaunchKernelGGL(k_bt_scan, dim3(1), dim3(256), 0, stream, cmap, best, evec);
  hipLaunchKernelGGL(k_bt_replay, dim3(NC), dim3(64), 0, stream, bptr, evec, out);
}

// Round 10
// 19401.474 us; speedup vs baseline: 3.2118x; 1.0112x over previous
//
#include <hip/hip_runtime.h>
#include <cstdint>
#include <cstddef>

// ---------------- problem constants ----------------
namespace {
constexpr int Bb = 8, Ss = 2048, Ee = 256, Hh = 256, G4 = 1024, Tt = 12;
constexpr int NTOK = Bb * Ss;              // 16384 rows
constexpr int NC = 256, LCH = 64;          // viterbi chunking: 256 chunks x 64 steps
constexpr float FNEG = -10000.0f;
constexpr int START_TAG = 10, STOP_TAG = 11;

// ---------------- workspace layout (bytes) ----------------
constexpr size_t OFF_XS    = 0;                         // [16384][256] f32 gathered embeddings
constexpr size_t SZ_XS     = (size_t)NTOK * Ee * 4;
constexpr size_t OFF_WT    = OFF_XS + SZ_XS;            // [2][256][1024] f32 w_ih transposed
constexpr size_t SZ_WT     = (size_t)2 * Ee * G4 * 4;
constexpr size_t OFF_XPF   = OFF_WT + SZ_WT;            // [2048][8][1024] f32 x-proj fwd (bias folded)
constexpr size_t SZ_XP     = (size_t)Ss * Bb * G4 * 4;
constexpr size_t OFF_XPB   = OFF_XPF + SZ_XP;
constexpr size_t OFF_HF    = OFF_XPB + SZ_XP;           // [2048][8][256] f32 fwd hidden history
constexpr size_t SZ_H      = (size_t)Ss * Bb * Hh * 4;
constexpr size_t OFF_HB    = OFF_HF + SZ_H;
constexpr size_t OFF_FEATS = OFF_HB + SZ_H;             // [16384][12] f32
constexpr size_t SZ_FEATS  = (size_t)NTOK * Tt * 4;
constexpr size_t OFF_PMAT  = OFF_FEATS + SZ_FEATS;      // [256][144] f32 chunk max-plus mats
constexpr size_t SZ_PMAT   = (size_t)NC * 144 * 4;
constexpr size_t OFF_FVIN  = OFF_PMAT + SZ_PMAT;        // [256][12] f32 chunk-entry fv
constexpr size_t SZ_FVIN   = (size_t)NC * Tt * 4;
constexpr size_t OFF_BPTR  = OFF_FVIN + SZ_FVIN;        // [16384] u64 packed 12x4bit backptrs
constexpr size_t SZ_BPTR   = (size_t)NTOK * 8;
constexpr size_t OFF_CMAP  = OFF_BPTR + SZ_BPTR;        // [256][12] int chunk composed maps
constexpr size_t SZ_CMAP   = (size_t)NC * Tt * 4;
constexpr size_t OFF_EVEC  = OFF_CMAP + SZ_CMAP;        // [256] int tag at chunk-end
constexpr size_t SZ_EVEC   = (size_t)NC * 4;
constexpr size_t OFF_BEST  = OFF_EVEC + SZ_EVEC;        // [1] int
constexpr size_t SZ_BEST   = 256;
constexpr size_t OFF_HD    = OFF_BEST + SZ_BEST;        // (legacy, unused)
constexpr size_t SZ_HD     = (size_t)2 * 2 * 2048 * 8;
constexpr size_t OFF_EPOCH = OFF_HD + SZ_HD;            // (legacy, unused)
constexpr size_t SZ_EPOCH  = 256;
constexpr size_t WS_NEED   = OFF_EPOCH + SZ_EPOCH;      // ~179 MB (unchanged)

// w_hh^T [2][256][1024] (2 MB) lives in the XS region, which is dead after
// k_inproj consumes xs. Written by a second k_transpose dispatch that runs
// AFTER k_inproj (stream-ordered), read by k_lstm via normal loads.
constexpr size_t OFF_WHT   = OFF_XS;
static_assert(2 * 256 * 1024 * 4 <= SZ_XS, "whhT fits in xs region");

// k_lstm weight tiers (per 256-thread WG, one WG per (dir,batch) chain):
//   KR rows of W_hh^T in VGPRs  (float4/thread/row -> 4*KR VGPRs)
//   KL rows in LDS              (4 KB/row)
//   KS rows streamed from L2    (496 KB/step, L2-resident read-only)
// R14 vs R13: 256-thread block (4 waves = 1 wave/SIMD) -> architectural
// VGPR cap 512/thread. R12 (512,2)->112 and R13 (512,1)->128 proved the
// allocator refuses >128 regs for 8-wave blocks and spills the weight
// array (R13 arithmetic: 889KB/step effective through L1 at ~95GB/s/CU
// = the measured 9.18us/step). At 1 wave/SIMD learn_hip measured no-spill
// allocations through 450 regs, so float4 wreg[96] = 384 (+~35 overhead)
// should finally be RESIDENT. Each thread owns 4 consecutive z-columns.
constexpr int KR = 96, KL = 36, KS = 256 - KR - KL;   // 124
static_assert(KR % 4 == 0 && KL % 4 == 0 && KS % 4 == 0, "tiers 4-aligned");

__device__ __forceinline__ float4 f4fma(float a, float4 b, float4 c) {
  c.x = fmaf(a, b.x, c.x); c.y = fmaf(a, b.y, c.y);
  c.z = fmaf(a, b.z, c.z); c.w = fmaf(a, b.w, c.w);
  return c;
}
}  // namespace

// ---------------- gather embeddings: xs[r=t*8+b][k] = emb[sentence[b][t]][k] ----------------
__global__ __launch_bounds__(256) void k_gather(const int* __restrict__ sent,
                                                const float* __restrict__ emb,
                                                float* __restrict__ xs) {
  int rr = threadIdx.x >> 3, p = threadIdx.x & 7;
  int r = blockIdx.x * 32 + rr;
  int tg = r >> 3, bg = r & 7;
  int tok = sent[bg * Ss + tg];
  const float4* src = (const float4*)(emb + (size_t)tok * Ee) + p * 8;
  float4* dst = (float4*)(xs + (size_t)r * Ee) + p * 8;
#pragma unroll
  for (int i = 0; i < 8; ++i) dst[i] = src[i];
}

// ---------------- transpose [1024][256] -> [k][n] (used for w_ih AND w_hh) ----------------
__global__ __launch_bounds__(256) void k_transpose(const float* __restrict__ w_f,
                                                   const float* __restrict__ w_b,
                                                   float* __restrict__ wT) {
  int idx = blockIdx.x * 256 + threadIdx.x;
  if (idx >= 2 * Ee * G4) return;
  int d = idx >> 18;
  int rem = idx & 262143;
  int k = rem >> 10, n = rem & 1023;
  const float* w = d ? w_b : w_f;
  wT[idx] = w[n * Ee + k];
}

// ---------------- input projection GEMM: xp[r][n] = xs[r][:] . w_ih[n][:] + bias[n] ----------------
__global__ __launch_bounds__(256) void k_inproj(const float* __restrict__ xs,
                                                const float* __restrict__ wT,
                                                const float* __restrict__ b_f,
                                                const float* __restrict__ b_b,
                                                float* __restrict__ xpf,
                                                float* __restrict__ xpb) {
  const int dir = blockIdx.z;
  const float* wTd = wT + (size_t)dir * (Ee * G4);
  const float* bv = dir ? b_b : b_f;
  float* xp = dir ? xpb : xpf;
  const int rg = threadIdx.x >> 5, cg = threadIdx.x & 31;
  const int rbase = blockIdx.x * 32 + rg * 4;
  const int c0 = blockIdx.y * 128 + cg * 4;
  const float4* ap0 = (const float4*)(xs + (size_t)(rbase + 0) * Ee);
  const float4* ap1 = (const float4*)(xs + (size_t)(rbase + 1) * Ee);
  const float4* ap2 = (const float4*)(xs + (size_t)(rbase + 2) * Ee);
  const float4* ap3 = (const float4*)(xs + (size_t)(rbase + 3) * Ee);
  float4 acc0 = {0,0,0,0}, acc1 = {0,0,0,0}, acc2 = {0,0,0,0}, acc3 = {0,0,0,0};
#pragma unroll 4
  for (int k4 = 0; k4 < 64; ++k4) {
    float4 a0 = ap0[k4], a1 = ap1[k4], a2 = ap2[k4], a3 = ap3[k4];
    const float* wb = wTd + (size_t)(k4 * 4) * G4 + c0;
    float4 b0 = *(const float4*)(wb);
    float4 b1 = *(const float4*)(wb + G4);
    float4 b2 = *(const float4*)(wb + 2 * G4);
    float4 b3 = *(const float4*)(wb + 3 * G4);
    acc0 = f4fma(a0.x, b0, acc0); acc0 = f4fma(a0.y, b1, acc0);
    acc0 = f4fma(a0.z, b2, acc0); acc0 = f4fma(a0.w, b3, acc0);
    acc1 = f4fma(a1.x, b0, acc1); acc1 = f4fma(a1.y, b1, acc1);
    acc1 = f4fma(a1.z, b2, acc1); acc1 = f4fma(a1.w, b3, acc1);
    acc2 = f4fma(a2.x, b0, acc2); acc2 = f4fma(a2.y, b1, acc2);
    acc2 = f4fma(a2.z, b2, acc2); acc2 = f4fma(a2.w, b3, acc2);
    acc3 = f4fma(a3.x, b0, acc3); acc3 = f4fma(a3.y, b1, acc3);
    acc3 = f4fma(a3.z, b2, acc3); acc3 = f4fma(a3.w, b3, acc3);
  }
  float4 bias = *(const float4*)(bv + c0);
  acc0.x += bias.x; acc0.y += bias.y; acc0.z += bias.z; acc0.w += bias.w;
  acc1.x += bias.x; acc1.y += bias.y; acc1.z += bias.z; acc1.w += bias.w;
  acc2.x += bias.x; acc2.y += bias.y; acc2.z += bias.z; acc2.w += bias.w;
  acc3.x += bias.x; acc3.y += bias.y; acc3.z += bias.z; acc3.w += bias.w;
  *(float4*)(xp + (size_t)(rbase + 0) * G4 + c0) = acc0;
  *(float4*)(xp + (size_t)(rbase + 1) * G4 + c0) = acc1;
  *(float4*)(xp + (size_t)(rbase + 2) * G4 + c0) = acc2;
  *(float4*)(xp + (size_t)(rbase + 3) * G4 + c0) = acc3;
}

// ---------------- persistent bidirectional LSTM: BATCH-SPLIT, NO EXCHANGE ----------------
// 16 WGs, one per (dir, batch) chain, ZERO inter-WG communication (R4-R11:
// all cross-WG coherence paths bottom out at ~5-6.5us/step on this machine).
// h lives in LDS, c in registers; per-step sync is two __syncthreads.
// Weights 3-tiered: VGPR / LDS / L2-stream (see tier comment above).
// R14 thread map: 256 threads; thread t owns output columns n=4t..4t+3 of
// z[1024] (PyTorch gate order: rows 0-255=i, 256-511=f, 512-767=g,
// 768-1023=o). Gate phase: thread t owns channel t.
__global__ __launch_bounds__(256, 1) void k_lstm(
    const float* __restrict__ whhT,
    const float* __restrict__ h0, const float* __restrict__ c0,
    const float* __restrict__ xpf, const float* __restrict__ xpb,
    float* __restrict__ hist_f, float* __restrict__ hist_b) {
  __shared__ __align__(16) float h_lds[256];
  __shared__ __align__(16) float z_lds[1024];
  __shared__ __align__(16) float wlds[KL][1024];

  const int wg = blockIdx.x, dir = wg >> 3, b = wg & 7;
  const int t = threadIdx.x;
  const float* WT = whhT + (size_t)dir * (256 * 1024);
  const float* xp = dir ? xpb : xpf;
  float* hist = dir ? hist_b : hist_f;
  const int n0 = 4 * t;

  // tier 1: KR rows in registers (float4 per thread per row)
  float4 wreg[KR];
#pragma unroll
  for (int k = 0; k < KR; ++k)
    wreg[k] = *(const float4*)(WT + (size_t)k * 1024 + n0);
  // tier 2: KL rows into LDS
  for (int i = t; i < KL * 1024; i += 256)
    wlds[i >> 10][i & 1023] = WT[(size_t)(KR + (i >> 10)) * 1024 + (i & 1023)];
  // state
  h_lds[t] = h0[dir * 2048 + b * 256 + t];
  float c_reg = c0[dir * 2048 + b * 256 + t];
  __syncthreads();

  const float* WS = WT + (size_t)(KR + KL) * 1024;  // tier 3: streamed rows

  for (int s = 0; s < Ss; ++s) {
    const int tg = dir ? (Ss - 1 - s) : s;
    // xp prefetch (h-independent)
    float4 acc = *(const float4*)(xp + (size_t)tg * 8192 + b * 1024 + n0);
    // tier 1: registers
#pragma unroll
    for (int k4 = 0; k4 < KR / 4; ++k4) {
      float4 h4 = *(const float4*)&h_lds[k4 * 4];
      acc = f4fma(h4.x, wreg[k4 * 4 + 0], acc);
      acc = f4fma(h4.y, wreg[k4 * 4 + 1], acc);
      acc = f4fma(h4.z, wreg[k4 * 4 + 2], acc);
      acc = f4fma(h4.w, wreg[k4 * 4 + 3], acc);
    }
    // tier 2: LDS
#pragma unroll
    for (int k4 = 0; k4 < KL / 4; ++k4) {
      float4 h4 = *(const float4*)&h_lds[KR + k4 * 4];
      float4 w0 = *(const float4*)&wlds[k4 * 4 + 0][n0];
      float4 w1 = *(const float4*)&wlds[k4 * 4 + 1][n0];
      float4 w2 = *(const float4*)&wlds[k4 * 4 + 2][n0];
      float4 w3 = *(const float4*)&wlds[k4 * 4 + 3][n0];
      acc = f4fma(h4.x, w0, acc);
      acc = f4fma(h4.y, w1, acc);
      acc = f4fma(h4.z, w2, acc);
      acc = f4fma(h4.w, w3, acc);
    }
    // tier 3: streamed from L2 (bandwidth-bound; loads are h-independent)
#pragma unroll 4
    for (int k4 = 0; k4 < KS / 4; ++k4) {
      const float* wp = WS + (size_t)(k4 * 4) * 1024 + n0;
      float4 w0 = *(const float4*)(wp);
      float4 w1 = *(const float4*)(wp + 1024);
      float4 w2 = *(const float4*)(wp + 2048);
      float4 w3 = *(const float4*)(wp + 3072);
      float4 h4 = *(const float4*)&h_lds[KR + KL + k4 * 4];
      acc = f4fma(h4.x, w0, acc);
      acc = f4fma(h4.y, w1, acc);
      acc = f4fma(h4.z, w2, acc);
      acc = f4fma(h4.w, w3, acc);
    }
    *(float4*)&z_lds[n0] = acc;
    __syncthreads();  // B1: z complete; all h_lds reads of this step done
    {
      float zi = z_lds[t], zf = z_lds[256 + t];
      float zg = z_lds[512 + t], zo = z_lds[768 + t];
      float iv = 1.0f / (1.0f + expf(-zi));
      float fv = 1.0f / (1.0f + expf(-zf));
      float gv = tanhf(zg);
      float ov = 1.0f / (1.0f + expf(-zo));
      c_reg = fv * c_reg + iv * gv;
      float hv = ov * tanhf(c_reg);
      h_lds[t] = hv;
      hist[(size_t)tg * 2048 + b * 256 + t] = hv;
    }
    __syncthreads();  // B2: h_{s} ready for next step
  }
}

// ---------------- feats = [hf|hb] @ W_out^T + b_out ----------------
__global__ __launch_bounds__(256) void k_feats(const float* __restrict__ hist_f,
                                               const float* __restrict__ hist_b,
                                               const float* __restrict__ Wout,
                                               const float* __restrict__ bout,
                                               float* __restrict__ feats) {
  __shared__ float wsh[Tt * 512];
  __shared__ float bsh[Tt];
  for (int i = threadIdx.x; i < Tt * 512; i += 256) wsh[i] = Wout[i];
  if (threadIdx.x < Tt) bsh[threadIdx.x] = bout[threadIdx.x];
  __syncthreads();
  int r = blockIdx.x * 256 + threadIdx.x;
  int bq = r >> 11, sq = r & 2047;
  const float4* hf4 = (const float4*)(hist_f + (size_t)sq * 2048 + bq * Hh);
  const float4* hb4 = (const float4*)(hist_b + (size_t)sq * 2048 + bq * Hh);
  float acc[Tt];
#pragma unroll
  for (int j = 0; j < Tt; ++j) acc[j] = bsh[j];
  for (int k4 = 0; k4 < 64; ++k4) {
    float4 x = hf4[k4];
#pragma unroll
    for (int j = 0; j < Tt; ++j) {
      float4 w = *(const float4*)&wsh[j * 512 + k4 * 4];
      acc[j] = fmaf(x.x, w.x, fmaf(x.y, w.y, fmaf(x.z, w.z, fmaf(x.w, w.w, acc[j]))));
    }
  }
  for (int k4 = 0; k4 < 64; ++k4) {
    float4 x = hb4[k4];
#pragma unroll
    for (int j = 0; j < Tt; ++j) {
      float4 w = *(const float4*)&wsh[j * 512 + 256 + k4 * 4];
      acc[j] = fmaf(x.x, w.x, fmaf(x.y, w.y, fmaf(x.z, w.z, fmaf(x.w, w.w, acc[j]))));
    }
  }
#pragma unroll
  for (int j = 0; j < Tt; ++j) feats[(size_t)r * Tt + j] = acc[j];
}

// ---------------- Viterbi phase 1: per-chunk max-plus matrix product ----------------
__global__ __launch_bounds__(192) void k_vit_chunkmat(const float* __restrict__ feats,
                                                      const float* __restrict__ trans,
                                                      float* __restrict__ pmat) {
  __shared__ float R[2][144];
  __shared__ float fe[LCH * Tt];
  __shared__ float ts[144];
  const int t = threadIdx.x, c = blockIdx.x;
  for (int i = t; i < LCH * Tt; i += 192) fe[i] = feats[(size_t)c * LCH * Tt + i];
  if (t < 144) ts[t] = trans[t];
  __syncthreads();
  int j = 0, k = 0;
  float trow[12];
  if (t < 144) {
    j = t / 12; k = t - j * 12;
#pragma unroll
    for (int m = 0; m < 12; ++m) trow[m] = ts[j * 12 + m];
    R[0][t] = ts[t] + fe[j];  // A_{t0}
  }
  __syncthreads();
  for (int i = 1; i < LCH; ++i) {
    int p = (i - 1) & 1;
    if (t < 144) {
      float m = trow[0] + R[p][k];
#pragma unroll
      for (int mm = 1; mm < 12; ++mm) m = fmaxf(m, trow[mm] + R[p][mm * 12 + k]);
      R[p ^ 1][t] = m + fe[i * 12 + j];
    }
    __syncthreads();
  }
  if (t < 144) pmat[(size_t)c * 144 + t] = R[(LCH - 1) & 1][t];
}

// ---------------- Viterbi phase 2: sequential scan over chunk matrices ----------------
__global__ __launch_bounds__(192) void k_vit_scan(const float* __restrict__ pmat,
                                                  const float* __restrict__ trans,
                                                  float* __restrict__ fvin,
                                                  float* __restrict__ dout,
                                                  int* __restrict__ best) {
  __shared__ float fv[12];
  __shared__ float sl[144];
  __shared__ float term[12];
  const int t = threadIdx.x;
  const int j = t / 12, k = t - j * 12;
  if (t < 12) fv[t] = (t == START_TAG) ? 0.0f : FNEG;
  float pv = (t < 144) ? pmat[t] : 0.0f;
  __syncthreads();
  for (int c = 0; c < NC; ++c) {
    if (t < 12) fvin[c * 12 + t] = fv[t];
    float pnext = (t < 144 && c + 1 < NC) ? pmat[(size_t)(c + 1) * 144 + t] : 0.0f;
    if (t < 144) sl[t] = pv + fv[k];
    __syncthreads();
    if (t < 12) {
      float m = sl[t * 12];
#pragma unroll
      for (int kk = 1; kk < 12; ++kk) m = fmaxf(m, sl[t * 12 + kk]);
      fv[t] = m;
    }
    __syncthreads();
    pv = pnext;
  }
  if (t < 12) term[t] = fv[t] + trans[STOP_TAG * 12 + t];
  __syncthreads();
  if (t == 0) {
    float m = term[0]; int a = 0;
    for (int q = 1; q < 12; ++q) { if (term[q] > m) { m = term[q]; a = q; } }
    dout[0] = m;
    best[0] = a;
  }
}

// ---------------- Viterbi phase 3: replay chunks -> packed backpointers ----------------
__global__ __launch_bounds__(64) void k_vit_replay(const float* __restrict__ feats,
                                                   const float* __restrict__ trans,
                                                   const float* __restrict__ fvin,
                                                   unsigned long long* __restrict__ bptr) {
  __shared__ float fe[LCH * Tt];
  __shared__ float fv[12];
  __shared__ int bpn[12];
  const int t = threadIdx.x, c = blockIdx.x;
  for (int i = t; i < LCH * Tt; i += 64) fe[i] = feats[(size_t)c * LCH * Tt + i];
  float trow[12];
  if (t < 12) {
#pragma unroll
    for (int m = 0; m < 12; ++m) trow[m] = trans[t * 12 + m];
    fv[t] = fvin[c * 12 + t];
  }
  __syncthreads();
  for (int i = 0; i < LCH; ++i) {
    float nm = 0.0f;
    if (t < 12) {
      float m = fv[0] + trow[0]; int a = 0;
#pragma unroll
      for (int k = 1; k < 12; ++k) {
        float v = fv[k] + trow[k];
        if (v > m) { m = v; a = k; }   // first-max wins, matches jnp.argmax
      }
      nm = m + fe[i * 12 + t];
      bpn[t] = a;
    }
    __syncthreads();
    if (t < 12) fv[t] = nm;
    if (t == 0) {
      unsigned long long bp = 0;
#pragma unroll
      for (int jq = 0; jq < 12; ++jq)
        bp |= (unsigned long long)(unsigned)bpn[jq] << (4 * jq);
      bptr[(size_t)c * LCH + i] = bp;
    }
    __syncthreads();
  }
}

// ---------------- backtrace phase A: compose per-chunk tag maps ----------------
__global__ __launch_bounds__(64) void k_bt_chunk(const unsigned long long* __restrict__ bptr,
                                                 int* __restrict__ cmap) {
  __shared__ unsigned long long bp[LCH];
  const int t = threadIdx.x, c = blockIdx.x;
  if (t < LCH) bp[t] = bptr[(size_t)c * LCH + t];
  __syncthreads();
  if (t < 12) {
    int v = t;
    for (int i = LCH - 1; i >= 0; --i) v = (int)((bp[i] >> (4 * v)) & 15ULL);
    cmap[c * 12 + t] = v;
  }
}

// ---------------- backtrace phase B: scan chunk maps ----------------
__global__ __launch_bounds__(256) void k_bt_scan(const int* __restrict__ cmap,
                                                 const int* __restrict__ best,
                                                 int* __restrict__ evec) {
  __shared__ int cm[NC * 12];
  __shared__ int es[NC];
  const int t = threadIdx.x;
  for (int i = t; i < NC * 12; i += 256) cm[i] = cmap[i];
  __syncthreads();
  if (t == 0) {
    int tag = best[0];
    es[NC - 1] = tag;
    for (int c = NC - 1; c >= 1; --c) { tag = cm[c * 12 + tag]; es[c - 1] = tag; }
  }
  __syncthreads();
  evec[t] = es[t];
}

// ---------------- backtrace phase C: emit path ----------------
__global__ __launch_bounds__(64) void k_bt_replay(const unsigned long long* __restrict__ bptr,
                                                  const int* __restrict__ evec,
                                                  float* __restrict__ dout) {
  __shared__ unsigned long long bp[LCH];
  __shared__ int tgs[LCH];
  const int t = threadIdx.x, c = blockIdx.x;
  if (t < LCH) bp[t] = bptr[(size_t)c * LCH + t];
  __syncthreads();
  if (t == 0) {
    int tag = evec[c];  // tag at global index (c+1)*LCH
    for (int i = LCH - 1; i >= 0; --i) {
      tgs[i] = tag;                              // out[c*LCH+i] = tag_{c*LCH+i+1}
      tag = (int)((bp[i] >> (4 * tag)) & 15ULL);
    }
  }
  __syncthreads();
  dout[1 + c * LCH + t] = (float)tgs[t];
}

// ---------------- launcher ----------------
extern "C" void kernel_launch(void* const* d_in, const int* in_sizes, int n_in,
                              void* d_out, int out_size, void* d_ws, size_t ws_size,
                              hipStream_t stream) {
  const int*   sent = (const int*)d_in[0];
  const float* emb  = (const float*)d_in[1];
  const float* wihf = (const float*)d_in[2];
  const float* whhf = (const float*)d_in[3];
  const float* bf   = (const float*)d_in[4];
  const float* wihb = (const float*)d_in[5];
  const float* whhb = (const float*)d_in[6];
  const float* bb   = (const float*)d_in[7];
  const float* h0   = (const float*)d_in[8];
  const float* c0   = (const float*)d_in[9];
  const float* Wout = (const float*)d_in[10];
  const float* bout = (const float*)d_in[11];
  const float* trans= (const float*)d_in[12];
  float* out = (float*)d_out;
  char* ws = (char*)d_ws;
  if (ws_size < WS_NEED) return;  // workspace too small: bail (visible as wrong output)

  float* xs    = (float*)(ws + OFF_XS);
  float* wT    = (float*)(ws + OFF_WT);
  float* xpf   = (float*)(ws + OFF_XPF);
  float* xpb   = (float*)(ws + OFF_XPB);
  float* hf    = (float*)(ws + OFF_HF);
  float* hb    = (float*)(ws + OFF_HB);
  float* feats = (float*)(ws + OFF_FEATS);
  float* pmat  = (float*)(ws + OFF_PMAT);
  float* fvin  = (float*)(ws + OFF_FVIN);
  unsigned long long* bptr = (unsigned long long*)(ws + OFF_BPTR);
  int*   cmap  = (int*)(ws + OFF_CMAP);
  int*   evec  = (int*)(ws + OFF_EVEC);
  int*   best  = (int*)(ws + OFF_BEST);
  float* whT   = (float*)(ws + OFF_WHT);   // overlaps xs: written after k_inproj

  hipLaunchKernelGGL(k_gather, dim3(512), dim3(256), 0, stream, sent, emb, xs);
  hipLaunchKernelGGL(k_transpose, dim3(2048), dim3(256), 0, stream, wihf, wihb, wT);
  hipLaunchKernelGGL(k_inproj, dim3(512, 8, 2), dim3(256), 0, stream,
                     xs, wT, bf, bb, xpf, xpb);
  // xs is dead now; transpose w_hh into its region for k_lstm
  hipLaunchKernelGGL(k_transpose, dim3(2048), dim3(256), 0, stream, whhf, whhb, whT);
  hipLaunchKernelGGL(k_lstm, dim3(16), dim3(256), 0, stream,
                     whT, h0, c0, xpf, xpb, hf, hb);
  hipLaunchKernelGGL(k_feats, dim3(64), dim3(256), 0, stream, hf, hb, Wout, bout, feats);
  hipLaunchKernelGGL(k_vit_chunkmat, dim3(NC), dim3(192), 0, stream, feats, trans, pmat);
  hipLaunchKernelGGL(k_vit_scan, dim3(1), dim3(192), 0, stream, pmat, trans, fvin, out, best);
  hipLaunchKernelGGL(k_vit_replay, dim3(NC), dim3(64), 0, stream, feats, trans, fvin, bptr);
  hipLaunchKernelGGL(k_bt_chunk, dim3(NC), dim3(64), 0, stream, bptr, cmap);
  hipLaunchKernelGGL(k_bt_scan, dim3(1), dim3(256), 0, stream, cmap, best, evec);
  hipLaunchKernelGGL(k_bt_replay, dim3(NC), dim3(64), 0, stream, bptr, evec, out);
}